// Round 13
// baseline (396.926 us; speedup 1.0000x reference)
//
#include <hip/hip_runtime.h>

// LTV Kalman filter, GPU-restructured (Woodbury + parallel Riccati).
// R7: H==G -> Hg dropped. k2b: exact reg-GJ + logdet. k3: OWN=4, WARM=12.
// R8 (478.8 -> 448.6): k2b Phase C VALU-lean 256-thread GJ.
// R11 (448.6 -> 375.9): k0 diag fast path.
// R13 (REGRESSED -> 407.8): k2a P_pred in global scratch. Occupancy 38->66%
// but FETCH/WRITE exploded -> memory-bound. Reverted.
// R14 (REGRESSED -> 389.1): k2a Ub-free ping-pong. Occupancy 66%, 1 round,
// but +36 near-empty barriers -> 76.8 -> 85.3us. LESSON: all 1024 blocks are
// co-resident; k2a time = per-block serial chain = (#heavy segments) x
// (LDS->MFMA segment latency ~1.37us). Occupancy is NOT the lever.
// R19: k2a Newton via PRODUCT FORM. Y0=a*M, Z_n=2I-Y_n: X9 = a*Z0..Z8 with
// P<-P*Z and Y<-Y*Z sharing operand Z -> the two matmuls per iteration MERGE
// into ONE heavy segment (2 barriers each, same count as R11, but half the
// serial LDS-latency exposures: ~24 -> ~16 heavy segs/step). Mt only seeds
// Y0 -> 4 LDS mats (Pl, Yl, Zt, Pp16) = 39264B. W = a*(PROD Z)*P_pred.
// Predict k2a 76.8 -> 60-70us; fallback: >=77 => revert k2a to R11.
// R20: identical resubmit of R19 — round 12 hit "MI355X container failed
// twice" (infra; kernel audited for fault/deadlock sources, none found).

#define TT 2048
#define NN 256
#define KKD 64
#define PIT 68      // fp32 LDS pitch
#define PB 72       // bf16 LDS pitch
#define PL 264      // bf16 LDS pitch for k1 64x256 L^T tiles
#define LOG2PI 1.8378770664093453f

typedef unsigned short u16;
typedef unsigned int u32;
typedef __attribute__((ext_vector_type(8))) short short8;
typedef __attribute__((ext_vector_type(4))) float f32x4;

__device__ __forceinline__ float bf2f(u16 u) {
  u32 x = ((u32)u) << 16;
  return __uint_as_float(x);
}
__device__ __forceinline__ u16 f2bf(float f) {
  u32 u = __float_as_uint(f);
  u32 r = (u + 0x7fffu + ((u >> 16) & 1u)) >> 16;
  return (u16)r;
}
__device__ __forceinline__ u32 pack2(float a, float b) {
  return (u32)f2bf(a) | ((u32)f2bf(b) << 16);
}
__device__ __forceinline__ float4 ldF4(const float* p) { return *(const float4*)p; }
__device__ __forceinline__ float fin(float v) { return isfinite(v) ? v : 0.f; }
__device__ __forceinline__ float frcp(float x) {
  float r;
  asm("v_rcp_f32 %0, %1" : "=v"(r) : "v"(x));
  return r;
}

// ---------------- K0: scalars ----------------
// R11: isDiag computed FIRST; diag => sig = |a0| exactly (skips B = A^T*A and
// the 64-iter power iteration). Non-diag path unchanged.
__global__ __launch_bounds__(256) void k0(const float* __restrict__ Araw,
                                          const float* __restrict__ logQ,
                                          const float* __restrict__ logR,
                                          float* hdr, float* Qd, float* Asc, u16* Ab16) {
  __shared__ __align__(16) float Bm[64 * PIT];
  __shared__ __align__(16) float red[256];
  __shared__ __align__(16) float vv[64];
  int tid = threadIdx.x;
  if (tid < 64) Qd[tid] = expf(logQ[tid]);
  float r = expf(logR[tid]);
  red[tid] = logf(r + 1e-4f);
  __syncthreads();
  for (int o = 128; o; o >>= 1) {
    if (tid < o) red[tid] += red[tid + o];
    __syncthreads();
  }
  if (tid == 0) hdr[2] = red[0];
  __syncthreads();
  float a0 = Araw[0];
  float okf = 1.0f;
  for (int u = 0; u < 16; ++u) {
    int idx = tid * 16 + u;
    int i = idx >> 6, j = idx & 63;
    float v = Araw[idx];
    bool good = (i == j) ? (v == a0) : (v == 0.0f);
    if (!good) okf = 0.0f;
  }
  red[tid] = okf;
  __syncthreads();
  for (int o = 128; o; o >>= 1) {
    if (tid < o) red[tid] = fminf(red[tid], red[tid + o]);
    __syncthreads();
  }
  float isDiag = red[0];
  __syncthreads();
  float sig;
  if (isDiag != 0.f) {
    sig = fabsf(a0);
  } else {
    for (int u = 0; u < 16; ++u) {
      int idx = tid * 16 + u;
      int i = idx >> 6, j = idx & 63;
      float s = 0.f;
      for (int k = 0; k < 64; ++k) s += Araw[k * 64 + i] * Araw[k * 64 + j];
      Bm[i * PIT + j] = s;
    }
    __syncthreads();
    if (tid < 64) {
      vv[tid] = 1.0f;
      float lam = 0.f;
      for (int it = 0; it < 64; ++it) {
        float ui = 0.f;
        for (int k = 0; k < 64; ++k) ui += Bm[tid * PIT + k] * vv[k];
        float s = ui * ui;
        for (int o = 32; o; o >>= 1) s += __shfl_down(s, o);
        float n2 = __shfl(s, 0);
        float nr = sqrtf(fmaxf(n2, 1e-30f));
        vv[tid] = ui / nr;
        lam = nr;
      }
      if (tid == 0) red[0] = lam;
    }
    __syncthreads();
    sig = sqrtf(fmaxf(red[0], 0.f));
  }
  float scale = 0.98f / (sig + 1e-6f);
  if (tid == 0) {
    hdr[0] = scale * a0;
    hdr[1] = isDiag;
    hdr[3] = sig;
  }
  for (int u = 0; u < 16; ++u) {
    int idx = tid * 16 + u;
    float v = scale * Araw[idx];
    Asc[idx] = v;
    Ab16[idx] = f2bf(v);
  }
}

// ---------------- K1: per-t Woodbury precompute via MFMA (S and G only) ----
__global__ __launch_bounds__(512) void k1(const float* __restrict__ obs,
                                          const float* __restrict__ Lam,
                                          const float* __restrict__ logR,
                                          u16* __restrict__ Sg, u16* __restrict__ Gg,
                                          float* __restrict__ bv,
                                          float* __restrict__ cv, float* __restrict__ aNv) {
  int t = blockIdx.x, tid = threadIdx.x;
  __shared__ __align__(16) u16 Lt[64 * PL];
  __shared__ __align__(16) u16 LtW[64 * PL];
  __shared__ __align__(16) float w1a[NN], w2a[NN], wya[NN];
  __shared__ __align__(16) float red[512];
  int lane = tid & 63, wv = tid >> 6;
  int ln = lane & 15, q = lane >> 4;

  float cpart = 0.f, apart = 0.f;
  if (tid < NN) {
    float y = obs[(size_t)t * NN + tid];
    float r = expf(logR[tid]);
    float re = r + 1e-4f;
    float w1 = 1.0f / re;
    bool m = (y != y);
    w1a[tid] = w1;
    w2a[tid] = m ? 0.f : w1;
    wya[tid] = m ? 0.f : (w1 * y);
    cpart = m ? 0.f : (w1 * y * y);
    apart = m ? 0.f : 1.f;
  }
  const float4* Lsrc = (const float4*)(Lam + (size_t)t * NN * KKD);
  for (int u = 0; u < 8; ++u) {
    int fl = u * 512 + tid;
    float4 v = Lsrc[fl];
    int n = fl >> 4, k0 = (fl & 15) * 4;
    Lt[(k0 + 0) * PL + n] = f2bf(v.x);
    Lt[(k0 + 1) * PL + n] = f2bf(v.y);
    Lt[(k0 + 2) * PL + n] = f2bf(v.z);
    Lt[(k0 + 3) * PL + n] = f2bf(v.w);
  }
  __syncthreads();

  const float* Ws[2] = {w1a, w2a};
  u16* Os[2] = {Sg + (size_t)t * 4096, Gg + (size_t)t * 4096};
#pragma unroll
  for (int m = 0; m < 2; ++m) {
    const float* W = Ws[m];
    for (int u = 0; u < 4; ++u) {
      int fl = u * 512 + tid;
      int row = fl >> 5, c8 = (fl & 31) * 8;
      ushort4 lo = *(const ushort4*)&Lt[row * PL + c8];
      ushort4 hi = *(const ushort4*)&Lt[row * PL + c8 + 4];
      float4 wa = ldF4(&W[c8]);
      float4 wb = ldF4(&W[c8 + 4]);
      ushort4 olo, ohi;
      olo.x = f2bf(bf2f(lo.x) * wa.x); olo.y = f2bf(bf2f(lo.y) * wa.y);
      olo.z = f2bf(bf2f(lo.z) * wa.z); olo.w = f2bf(bf2f(lo.w) * wa.w);
      ohi.x = f2bf(bf2f(hi.x) * wb.x); ohi.y = f2bf(bf2f(hi.y) * wb.y);
      ohi.z = f2bf(bf2f(hi.z) * wb.z); ohi.w = f2bf(bf2f(hi.w) * wb.w);
      *(ushort4*)&LtW[row * PL + c8] = olo;
      *(ushort4*)&LtW[row * PL + c8 + 4] = ohi;
    }
    __syncthreads();
    u16* O = Os[m];
#pragma unroll
    for (int tl = 0; tl < 2; ++tl) {
      int td = wv + tl * 8, ti = td >> 2, tj = td & 3;
      f32x4 acc = {0.f, 0.f, 0.f, 0.f};
#pragma unroll
      for (int n0 = 0; n0 < 256; n0 += 32)
        acc = __builtin_amdgcn_mfma_f32_16x16x32_bf16(
            *(const short8*)&Lt[(ti * 16 + ln) * PL + n0 + q * 8],
            *(const short8*)&LtW[(tj * 16 + ln) * PL + n0 + q * 8], acc, 0, 0, 0);
      int col = tj * 16 + ln, rb = ti * 16 + q * 4;
#pragma unroll
      for (int r = 0; r < 4; ++r) O[(rb + r) * 64 + col] = f2bf(acc[r]);
    }
    __syncthreads();
  }

  {
    int k = tid >> 3, seg = tid & 7;
    float s = 0.f;
    for (int n = seg * 32; n < seg * 32 + 32; n += 4) {
      ushort4 l4 = *(const ushort4*)&Lt[k * PL + n];
      float4 wy = ldF4(&wya[n]);
      s += bf2f(l4.x) * wy.x + bf2f(l4.y) * wy.y + bf2f(l4.z) * wy.z + bf2f(l4.w) * wy.w;
    }
    red[tid] = s;
  }
  __syncthreads();
  if (tid < 64) {
    float acc = 0.f;
#pragma unroll
    for (int s = 0; s < 8; ++s) acc += red[tid * 8 + s];
    bv[(size_t)t * 64 + tid] = acc;
  }
  __syncthreads();
  red[tid] = cpart;
  __syncthreads();
  for (int o = 256; o; o >>= 1) {
    if (tid < o) red[tid] += red[tid + o];
    __syncthreads();
  }
  if (tid == 0) cv[t] = red[0];
  __syncthreads();
  red[tid] = apart;
  __syncthreads();
  for (int o = 256; o; o >>= 1) {
    if (tid < o) red[tid] += red[tid + o];
    __syncthreads();
  }
  if (tid == 0) aNv[t] = red[0];
}

// ---------------- MFMA fragment helpers (16x16x32 bf16) ----------------
__device__ __forceinline__ f32x4 mmLL(const u16* A, const u16* B, int ti, int tj,
                                      int ln, int q, f32x4 acc) {
  int ao = (ti * 16 + ln) * PB + q * 8;
  int bo = (tj * 16 + ln) * PB + q * 8;
#pragma unroll
  for (int k0 = 0; k0 < 64; k0 += 32)
    acc = __builtin_amdgcn_mfma_f32_16x16x32_bf16(*(const short8*)(A + ao + k0),
                                                  *(const short8*)(B + bo + k0), acc, 0, 0, 0);
  return acc;
}
__device__ __forceinline__ f32x4 mmLG(const u16* A, const u16* __restrict__ Bg, int ti,
                                      int tj, int ln, int q, f32x4 acc) {
  int ao = (ti * 16 + ln) * PB + q * 8;
  const u16* bp = Bg + (tj * 16 + ln) * 64 + q * 8;
#pragma unroll
  for (int k0 = 0; k0 < 64; k0 += 32)
    acc = __builtin_amdgcn_mfma_f32_16x16x32_bf16(*(const short8*)(A + ao + k0),
                                                  *(const short8*)(bp + k0), acc, 0, 0, 0);
  return acc;
}
__device__ __forceinline__ f32x4 mmGL(const u16* __restrict__ Ag, const u16* B, int ti,
                                      int tj, int ln, int q, f32x4 acc) {
  const u16* ap = Ag + (ti * 16 + ln) * 64 + q * 8;
  int bo = (tj * 16 + ln) * PB + q * 8;
#pragma unroll
  for (int k0 = 0; k0 < 64; k0 += 32)
    acc = __builtin_amdgcn_mfma_f32_16x16x32_bf16(*(const short8*)(ap + k0),
                                                  *(const short8*)(B + bo + k0), acc, 0, 0, 0);
  return acc;
}
__device__ __forceinline__ void stLDS(u16* Buf, int ti, int tj, int ln, int q, f32x4 v) {
  int col = tj * 16 + ln, rb = ti * 16 + q * 4;
#pragma unroll
  for (int r = 0; r < 4; ++r) Buf[(rb + r) * PB + col] = f2bf(v[r]);
}

// ---------------- K2a: warm-up sweep, product-form Newton inverse ----------
// R19: X = M^-1 ~= a * Z0*Z1*...*Z8 with Y0 = a*M, Z_n = 2I - Y_n,
// Y_{n+1} = Y_n*Z_n. Both P<-P*Z and Y<-Y*Z read the SAME Zt operand ->
// merged into one heavy segment per iteration. LDS: Pl, Yl, Zt, Pp16.
// Zt initially holds M^T for the power iteration, then Z_n^T.
__global__ __launch_bounds__(512, 8) void k2a(const u16* __restrict__ Sg,
                                              u16* __restrict__ Pout,
                                              const float* __restrict__ hdr,
                                              const float* __restrict__ Qd,
                                              const u16* __restrict__ Ab16) {
  int t0 = blockIdx.x * 2, tid = threadIdx.x;
  int lane = tid & 63, w = tid >> 6;
  int ln = lane & 15, q = lane >> 4;

  __shared__ __align__(16) u16 Pp16[64 * PB];  // P_prev / P_pred
  __shared__ __align__(16) u16 Pl[64 * PB];    // product accumulator, row-major
  __shared__ __align__(16) u16 Yl[64 * PB];    // Y_n, row-major
  __shared__ __align__(16) u16 Zt[64 * PB];    // M^T then Z_n^T
  __shared__ __align__(16) float pw[600];      // part[512] + v[72] + scalars

  float* part = pw;
  float* v = pw + 512;

  float aS = hdr[0];
  bool diag = (hdr[1] != 0.f);
  int row = tid >> 3, cg = tid & 7;

  for (int st = 0; st < 2; ++st) {
    int t = t0 + st;

    // ---- Phase A: P_pred -> Pp16 ----
    if (st == 0) {
      float pinit = (t == 0) ? 1.f : 0.15f;
      if (diag) {
        float a2 = aS * aS;
        float qr = Qd[row];
        uint4 o;
#pragma unroll
        for (int u = 0; u < 8; u += 2) {
          float va = ((cg * 8 + u == row) ? (a2 * pinit + qr) : 0.f);
          float vb = ((cg * 8 + u + 1 == row) ? (a2 * pinit + qr) : 0.f);
          ((u32*)&o)[u >> 1] = pack2(va, vb);
        }
        *(uint4*)&Pp16[row * PB + cg * 8] = o;
        __syncthreads();
      } else {
        uint4 o;
#pragma unroll
        for (int u = 0; u < 8; u += 2) {
          float va = (cg * 8 + u == row) ? pinit : 0.f;
          float vb = (cg * 8 + u + 1 == row) ? pinit : 0.f;
          ((u32*)&o)[u >> 1] = pack2(va, vb);
        }
        *(uint4*)&Pp16[row * PB + cg * 8] = o;
        __syncthreads();
#pragma unroll
        for (int tl = 0; tl < 2; ++tl) {
          int td = w + tl * 8, ti = td >> 2, tj = td & 3;
          f32x4 acc = {0.f, 0.f, 0.f, 0.f};
          acc = mmGL(Ab16, Pp16, ti, tj, ln, q, acc);
          stLDS(Pl, ti, tj, ln, q, acc);   // temp A*P in Pl
        }
        __syncthreads();
#pragma unroll
        for (int tl = 0; tl < 2; ++tl) {
          int td = w + tl * 8, ti = td >> 2, tj = td & 3;
          f32x4 acc = {0.f, 0.f, 0.f, 0.f};
          acc = mmLG(Pl, Ab16, ti, tj, ln, q, acc);
          int col = tj * 16 + ln, rb = ti * 16 + q * 4;
#pragma unroll
          for (int r = 0; r < 4; ++r) {
            float vv = acc[r] + ((rb + r) == col ? Qd[rb + r] : 0.f);
            Pp16[(rb + r) * PB + col] = f2bf(vv);
          }
        }
        __syncthreads();
      }
    } else {
      // P_prev already in Pp16 (posterior of t-1)
      if (diag) {
        float a2 = aS * aS;
        float qr = Qd[row];
        uint4 raw = *(const uint4*)&Pp16[row * PB + cg * 8];
        float pv[8];
        pv[0] = bf2f((u16)(raw.x & 0xffff)); pv[1] = bf2f((u16)(raw.x >> 16));
        pv[2] = bf2f((u16)(raw.y & 0xffff)); pv[3] = bf2f((u16)(raw.y >> 16));
        pv[4] = bf2f((u16)(raw.z & 0xffff)); pv[5] = bf2f((u16)(raw.z >> 16));
        pv[6] = bf2f((u16)(raw.w & 0xffff)); pv[7] = bf2f((u16)(raw.w >> 16));
        uint4 o;
#pragma unroll
        for (int u = 0; u < 8; u += 2) {
          float va = a2 * pv[u] + ((cg * 8 + u == row) ? qr : 0.f);
          float vb = a2 * pv[u + 1] + ((cg * 8 + u + 1 == row) ? qr : 0.f);
          ((u32*)&o)[u >> 1] = pack2(va, vb);
        }
        __syncthreads();  // all reads of Pp16 done before overwrite
        *(uint4*)&Pp16[row * PB + cg * 8] = o;
        __syncthreads();
      } else {
#pragma unroll
        for (int tl = 0; tl < 2; ++tl) {
          int td = w + tl * 8, ti = td >> 2, tj = td & 3;
          f32x4 acc = {0.f, 0.f, 0.f, 0.f};
          acc = mmGL(Ab16, Pp16, ti, tj, ln, q, acc);
          stLDS(Pl, ti, tj, ln, q, acc);
        }
        __syncthreads();
#pragma unroll
        for (int tl = 0; tl < 2; ++tl) {
          int td = w + tl * 8, ti = td >> 2, tj = td & 3;
          f32x4 acc = {0.f, 0.f, 0.f, 0.f};
          acc = mmLG(Pl, Ab16, ti, tj, ln, q, acc);
          int col = tj * 16 + ln, rb = ti * 16 + q * 4;
#pragma unroll
          for (int r = 0; r < 4; ++r) {
            float vv = acc[r] + ((rb + r) == col ? Qd[rb + r] : 0.f);
            Pp16[(rb + r) * PB + col] = f2bf(vv);
          }
        }
        __syncthreads();
      }
    }

    // ---- Phase B: M = I + P_pred * S -> Macc (regs) + M^T -> Zt ----
    f32x4 Macc[2];
#pragma unroll
    for (int tl = 0; tl < 2; ++tl) {
      int td = w + tl * 8, ti = td >> 2, tj = td & 3;
      f32x4 acc = {0.f, 0.f, 0.f, 0.f};
      acc = mmLG(Pp16, Sg + (size_t)t * 4096, ti, tj, ln, q, acc);
      int col = tj * 16 + ln, rb = ti * 16 + q * 4;
#pragma unroll
      for (int r = 0; r < 4; ++r) acc[r] += ((rb + r) == col ? 1.f : 0.f);
      Macc[tl] = acc;
      ushort4 o4;
      o4.x = f2bf(acc[0]); o4.y = f2bf(acc[1]);
      o4.z = f2bf(acc[2]); o4.w = f2bf(acc[3]);
      *(ushort4*)&Zt[col * PB + rb] = o4;  // M^T for power iteration
    }
    if (tid < 64) v[tid] = 1.f;
    __syncthreads();

    // ---- Power iteration: 3 matvecs on Zt (=M^T), lambda_est = max3/max2 --
    float mx[3];
    for (int itp = 0; itp < 3; ++itp) {
      int i = tid & 63, seg = tid >> 6;
      float s = 0.f;
#pragma unroll
      for (int u = 0; u < 8; ++u) {
        int k = seg * 8 + u;
        s += bf2f(Zt[k * PB + i]) * v[k];
      }
      part[tid] = s;
      __syncthreads();
      if (tid < 64) {
        float acc = 0.f;
#pragma unroll
        for (int sg = 0; sg < 8; ++sg) acc += part[tid + 64 * sg];
        v[tid] = acc;
        float m = fabsf(acc);
        for (int o = 32; o; o >>= 1) m = fmaxf(m, __shfl_down(m, o));
        if (tid == 0) pw[584 + itp] = m;
      }
      __syncthreads();
      mx[itp] = pw[584 + itp];
    }
    float lam = mx[2] / fmaxf(mx[1], 1e-20f);
    if (!isfinite(lam) || lam < 1.0f || lam > 1e4f) lam = 64.f;
    float alpha = 1.0f / (lam * 1.02f);

    // ---- Init: Y0 = a*M -> Yl; Z0 = 2I - Y0 -> Pl (row) and Zt (transp) ---
    // (Zt overwrite is safe: last power-iter barrier covers all Zt reads.)
#pragma unroll
    for (int tl = 0; tl < 2; ++tl) {
      int td = w + tl * 8, ti = td >> 2, tj = td & 3;
      int col = tj * 16 + ln, rb = ti * 16 + q * 4;
      ushort4 zt4;
#pragma unroll
      for (int r = 0; r < 4; ++r) {
        float y0 = alpha * Macc[tl][r];
        float z0 = (((rb + r) == col) ? 2.f : 0.f) - y0;
        Yl[(rb + r) * PB + col] = f2bf(y0);
        Pl[(rb + r) * PB + col] = f2bf(z0);
        ((u16*)&zt4)[r] = f2bf(z0);
      }
      *(ushort4*)&Zt[col * PB + rb] = zt4;
    }
    __syncthreads();

    // ---- seg0 (bootstrap): Y1 = Y0*Z0; Z1 = 2I - Y1 ----
    {
      f32x4 yn[2];
#pragma unroll
      for (int tl = 0; tl < 2; ++tl) {
        int td = w + tl * 8, ti = td >> 2, tj = td & 3;
        f32x4 z = {0.f, 0.f, 0.f, 0.f};
        yn[tl] = mmLL(Yl, Zt, ti, tj, ln, q, z);
      }
      __syncthreads();  // reads of Yl/Zt complete
#pragma unroll
      for (int tl = 0; tl < 2; ++tl) {
        int td = w + tl * 8, ti = td >> 2, tj = td & 3;
        int col = tj * 16 + ln, rb = ti * 16 + q * 4;
        ushort4 zt4;
#pragma unroll
        for (int r = 0; r < 4; ++r) {
          float yv = yn[tl][r];
          float zv = (((rb + r) == col) ? 2.f : 0.f) - yv;
          Yl[(rb + r) * PB + col] = f2bf(yv);
          ((u16*)&zt4)[r] = f2bf(zv);
        }
        *(ushort4*)&Zt[col * PB + rb] = zt4;
      }
      __syncthreads();
    }

    // ---- segs 1..7: P <- P*Z, Y <- Y*Z (merged), Z <- 2I - Ynew ----
    for (int it = 1; it < 8; ++it) {
      f32x4 pn[2], yn[2];
#pragma unroll
      for (int tl = 0; tl < 2; ++tl) {
        int td = w + tl * 8, ti = td >> 2, tj = td & 3;
        f32x4 z = {0.f, 0.f, 0.f, 0.f};
        pn[tl] = mmLL(Pl, Zt, ti, tj, ln, q, z);
        f32x4 z2 = {0.f, 0.f, 0.f, 0.f};
        yn[tl] = mmLL(Yl, Zt, ti, tj, ln, q, z2);
      }
      __syncthreads();  // reads of Pl/Yl/Zt complete
#pragma unroll
      for (int tl = 0; tl < 2; ++tl) {
        int td = w + tl * 8, ti = td >> 2, tj = td & 3;
        int col = tj * 16 + ln, rb = ti * 16 + q * 4;
        ushort4 zt4;
#pragma unroll
        for (int r = 0; r < 4; ++r) {
          float yv = yn[tl][r];
          float zv = (((rb + r) == col) ? 2.f : 0.f) - yv;
          Pl[(rb + r) * PB + col] = f2bf(pn[tl][r]);
          Yl[(rb + r) * PB + col] = f2bf(yv);
          ((u16*)&zt4)[r] = f2bf(zv);
        }
        *(ushort4*)&Zt[col * PB + rb] = zt4;
      }
      __syncthreads();
    }

    // ---- seg8: P <- P*Z (final; Y/Z not needed) ----
    {
      f32x4 pn[2];
#pragma unroll
      for (int tl = 0; tl < 2; ++tl) {
        int td = w + tl * 8, ti = td >> 2, tj = td & 3;
        f32x4 z = {0.f, 0.f, 0.f, 0.f};
        pn[tl] = mmLL(Pl, Zt, ti, tj, ln, q, z);
      }
      __syncthreads();  // reads of Pl complete
#pragma unroll
      for (int tl = 0; tl < 2; ++tl) {
        int td = w + tl * 8, ti = td >> 2, tj = td & 3;
        stLDS(Pl, ti, tj, ln, q, pn[tl]);
      }
      __syncthreads();
    }

    // ---- W = X * P_pred = a * (Pl * P_pred)  (P_pred symmetric) ----
    f32x4 pacc[2];
#pragma unroll
    for (int tl = 0; tl < 2; ++tl) {
      int td = w + tl * 8, ti = td >> 2, tj = td & 3;
      f32x4 acc = {0.f, 0.f, 0.f, 0.f};
      acc = mmLL(Pl, Pp16, ti, tj, ln, q, acc);
      int col = tj * 16 + ln, rb = ti * 16 + q * 4;
#pragma unroll
      for (int r = 0; r < 4; ++r) {
        float wv2 = fin(alpha * acc[r]);
        pacc[tl][r] = wv2;
        Pout[(size_t)t * 4096 + (rb + r) * 64 + col] = f2bf(wv2);
      }
    }
    if (st == 0) {
      __syncthreads();  // all waves done reading Pp16
#pragma unroll
      for (int tl = 0; tl < 2; ++tl) {
        int td = w + tl * 8, ti = td >> 2, tj = td & 3;
        int col = tj * 16 + ln, rb = ti * 16 + q * 4;
#pragma unroll
        for (int r = 0; r < 4; ++r)
          Pp16[(rb + r) * PB + col] = f2bf(pacc[tl][r]);
      }
      __syncthreads();
    }
  }
}

// ---------------- K2b: final sweep — exact GJ, W + logdet only -------------
__global__ __launch_bounds__(512) void k2b(const u16* __restrict__ Sg,
                                           const u16* __restrict__ Pin,
                                           u16* __restrict__ Wout,
                                           float* __restrict__ ldv,
                                           const float* __restrict__ hdr,
                                           const float* __restrict__ Qd,
                                           const u16* __restrict__ Ab16) {
  int t = blockIdx.x, tid = threadIdx.x;
  int lane = tid & 63, w = tid >> 6;
  int ln = lane & 15, q = lane >> 4;

  __shared__ __align__(16) u16 Pp16[64 * PB];
  __shared__ __align__(16) float M32[64 * PIT];
  __shared__ __align__(16) u16 XYb[64 * PB];
  __shared__ __align__(16) float colbuf[2][64];
  __shared__ __align__(16) float pivb[64];

  float aS = hdr[0];
  bool diag = (hdr[1] != 0.f);
  int row = tid >> 3, cg = tid & 7;

  // ---- Phase A: P_pred -> Pp16 ----
  float pv[8];
  if (t == 0) {
#pragma unroll
    for (int u = 0; u < 8; ++u) pv[u] = (cg * 8 + u == row) ? 1.f : 0.f;
  } else {
    uint4 raw = *(const uint4*)(Pin + (size_t)(t - 1) * 4096 + tid * 8);
    pv[0] = bf2f((u16)(raw.x & 0xffff)); pv[1] = bf2f((u16)(raw.x >> 16));
    pv[2] = bf2f((u16)(raw.y & 0xffff)); pv[3] = bf2f((u16)(raw.y >> 16));
    pv[4] = bf2f((u16)(raw.z & 0xffff)); pv[5] = bf2f((u16)(raw.z >> 16));
    pv[6] = bf2f((u16)(raw.w & 0xffff)); pv[7] = bf2f((u16)(raw.w >> 16));
  }
  if (diag) {
    float a2 = aS * aS;
    float qr = Qd[row];
    uint4 o;
#pragma unroll
    for (int u = 0; u < 8; u += 2) {
      float va = a2 * pv[u] + ((cg * 8 + u == row) ? qr : 0.f);
      float vb = a2 * pv[u + 1] + ((cg * 8 + u + 1 == row) ? qr : 0.f);
      ((u32*)&o)[u >> 1] = pack2(va, vb);
    }
    *(uint4*)&Pp16[row * PB + cg * 8] = o;
  } else {
    uint4 o;
    o.x = pack2(pv[0], pv[1]); o.y = pack2(pv[2], pv[3]);
    o.z = pack2(pv[4], pv[5]); o.w = pack2(pv[6], pv[7]);
    *(uint4*)&Pp16[row * PB + cg * 8] = o;
    __syncthreads();
#pragma unroll
    for (int tl = 0; tl < 2; ++tl) {
      int td = w + tl * 8, ti = td >> 2, tj = td & 3;
      f32x4 acc = {0.f, 0.f, 0.f, 0.f};
      acc = mmGL(Ab16, Pp16, ti, tj, ln, q, acc);
      stLDS(XYb, ti, tj, ln, q, acc);
    }
    __syncthreads();
#pragma unroll
    for (int tl = 0; tl < 2; ++tl) {
      int td = w + tl * 8, ti = td >> 2, tj = td & 3;
      f32x4 acc = {0.f, 0.f, 0.f, 0.f};
      acc = mmLG(XYb, Ab16, ti, tj, ln, q, acc);
      int col = tj * 16 + ln, rb = ti * 16 + q * 4;
#pragma unroll
      for (int r = 0; r < 4; ++r) {
        float vv = acc[r] + ((rb + r) == col ? Qd[rb + r] : 0.f);
        Pp16[(rb + r) * PB + col] = f2bf(vv);
      }
    }
  }
  __syncthreads();

  // ---- Phase B: M = I + P_pred * S ----
#pragma unroll
  for (int tl = 0; tl < 2; ++tl) {
    int td = w + tl * 8, ti = td >> 2, tj = td & 3;
    f32x4 acc = {0.f, 0.f, 0.f, 0.f};
    acc = mmLG(Pp16, Sg + (size_t)t * 4096, ti, tj, ln, q, acc);
    int col = tj * 16 + ln, rb = ti * 16 + q * 4;
#pragma unroll
    for (int r = 0; r < 4; ++r) M32[(rb + r) * PIT + col] = acc[r] + ((rb + r) == col ? 1.f : 0.f);
  }
  __syncthreads();

  // ---- Phase C: 256-thread register GJ + pivot capture ----
  int cig = tid >> 4;
  int cjg = tid & 15;
  int i0c = 4 * cig, j0c = 4 * cjg;
  float rr[4][4];
  if (tid < 256) {
#pragma unroll
    for (int k = 0; k < 4; ++k) {
      float4 a = ldF4(&M32[(i0c + k) * PIT + j0c]);
      rr[k][0] = a.x; rr[k][1] = a.y; rr[k][2] = a.z; rr[k][3] = a.w;
    }
    if (cjg == 0)
      *(float4*)&colbuf[0][i0c] = make_float4(rr[0][0], rr[1][0], rr[2][0], rr[3][0]);
  }
  __syncthreads();

  for (int g = 0; g < 16; ++g) {
#pragma unroll
    for (int u = 0; u < 4; ++u) {
      int j = g * 4 + u;
      if (tid < 256) {
        float4 pq = ldF4(&M32[j * PIT + j0c]);
        float pr4[4] = {pq.x, pq.y, pq.z, pq.w};
        float4 fv = ldF4(&colbuf[u & 1][i0c]);
        float fr[4] = {fv.x, fv.y, fv.z, fv.w};
        float piv = colbuf[u & 1][j];
        float pvv = copysignf(fmaxf(fabsf(piv), 1e-12f), piv);
        float prc = frcp(pvv);
        float fp[4];
#pragma unroll
        for (int k = 0; k < 4; ++k) fp[k] = fr[k] * prc;
#pragma unroll
        for (int k = 0; k < 4; ++k)
#pragma unroll
          for (int c = 0; c < 4; ++c) rr[k][c] = fmaf(-fp[k], pr4[c], rr[k][c]);
        if (cjg == g) {
#pragma unroll
          for (int k = 0; k < 4; ++k) rr[k][u] = -fp[k];
        }
        if (cig == g) {
#pragma unroll
          for (int c = 0; c < 4; ++c) rr[u][c] = pr4[c] * prc;
          if (cjg == g) { rr[u][u] = prc; pivb[j] = pvv; }
        }
        int jn = j + 1;
        if (jn < 64) {
          const int un = (u < 3) ? (u + 1) : 0;
          int gn = (u < 3) ? g : (g + 1);
          if (cig == gn)
            *(float4*)&M32[jn * PIT + j0c] =
                make_float4(rr[un][0], rr[un][1], rr[un][2], rr[un][3]);
          if (cjg == gn)
            *(float4*)&colbuf[(u + 1) & 1][i0c] =
                make_float4(rr[0][un], rr[1][un], rr[2][un], rr[3][un]);
        }
      }
      __syncthreads();
    }
  }

  // ---- Phase D: pack inverse regs -> XYb (bf16); parallel logdet ----
  if (tid < 256) {
#pragma unroll
    for (int k = 0; k < 4; ++k) {
      ushort4 o4;
      o4.x = f2bf(rr[k][0]); o4.y = f2bf(rr[k][1]);
      o4.z = f2bf(rr[k][2]); o4.w = f2bf(rr[k][3]);
      *(ushort4*)&XYb[(i0c + k) * PB + j0c] = o4;
    }
  }
  if (tid < 64) {
    float l = logf(fabsf(pivb[tid]));
    for (int o = 32; o; o >>= 1) l += __shfl_down(l, o);
    if (tid == 0) ldv[t] = fin(l);
  }
  __syncthreads();

  // ---- Phase E: W = X * P_pred -> Wout ----
#pragma unroll
  for (int tl = 0; tl < 2; ++tl) {
    int td = w + tl * 8, ti = td >> 2, tj = td & 3;
    f32x4 acc = {0.f, 0.f, 0.f, 0.f};
    acc = mmLL(XYb, Pp16, ti, tj, ln, q, acc);
    int col = tj * 16 + ln, rb = ti * 16 + q * 4;
#pragma unroll
    for (int r = 0; r < 4; ++r)
      Wout[(size_t)t * 4096 + (rb + r) * 64 + col] = f2bf(fin(acc[r]));
  }
}

// ---------------- K3: state + loglik, chunked parallel with warmup ----------
#define OWN 4
#define WARM 12
__global__ __launch_bounds__(256) void k3(const u16* __restrict__ Gg, const u16* __restrict__ Wg,
                                          const float* __restrict__ bv, const float* __restrict__ cv,
                                          const float* __restrict__ aNv, const float* __restrict__ ldv,
                                          const float* __restrict__ hdr, const float* __restrict__ Asc,
                                          float* __restrict__ out) {
  int b = blockIdx.x, tid = threadIdx.x;
  int t0 = b * OWN;
  int tw = t0 - WARM;
  if (tw < 0) tw = 0;
  __shared__ __align__(16) float z[64], zp[64], q[64], wv[64], uu[64], part[256];
  float aS = hdr[0];
  bool diag = (hdr[1] != 0.f);
  float slr = hdr[2];
  if (tid < 64) z[tid] = 0.f;
  __syncthreads();
  for (int t = tw; t < t0 + OWN; ++t) {
    bool own = (t >= t0);
    if (tid < 64) {
      if (diag)
        zp[tid] = aS * z[tid];
      else {
        float s = 0.f;
        for (int k = 0; k < 64; k += 4) {
          float4 a = ldF4(&Asc[tid * 64 + k]);
          s += a.x * z[k] + a.y * z[k + 1] + a.z * z[k + 2] + a.w * z[k + 3];
        }
        zp[tid] = s;
      }
    }
    __syncthreads();
    {
      int i = tid & 63, seg = tid >> 6;
      const u16* Gr = Gg + (size_t)t * 4096 + i * 64 + seg * 16;
      float s = 0.f;
      for (int u = 0; u < 16; u += 4) {
        ushort4 g4 = *(const ushort4*)(Gr + u);
        const float* zz = &zp[seg * 16 + u];
        s += bf2f(g4.x) * zz[0] + bf2f(g4.y) * zz[1] + bf2f(g4.z) * zz[2] + bf2f(g4.w) * zz[3];
      }
      part[tid] = s;
    }
    __syncthreads();
    if (tid < 64) {
      float qi = part[tid] + part[tid + 64] + part[tid + 128] + part[tid + 192];
      q[tid] = qi;
      wv[tid] = bv[(size_t)t * 64 + tid] - qi;
    }
    __syncthreads();
    {
      int i = tid & 63, seg = tid >> 6;
      const u16* Wr = Wg + (size_t)t * 4096 + i * 64 + seg * 16;
      float s = 0.f;
      for (int u = 0; u < 16; u += 4) {
        ushort4 g4 = *(const ushort4*)(Wr + u);
        const float* zz = &wv[seg * 16 + u];
        s += bf2f(g4.x) * zz[0] + bf2f(g4.y) * zz[1] + bf2f(g4.z) * zz[2] + bf2f(g4.w) * zz[3];
      }
      part[tid] = s;
    }
    __syncthreads();
    if (tid < 64) {
      float ui = part[tid] + part[tid + 64] + part[tid + 128] + part[tid + 192];
      uu[tid] = ui;
      float zi = zp[tid] + ui;
      z[tid] = isfinite(zi) ? zi : 0.f;
    }
    __syncthreads();
    if (tid < 64) {
      float bz = bv[(size_t)t * 64 + tid] * zp[tid];
      float zq = zp[tid] * q[tid];
      float wu = wv[tid] * uu[tid];
      for (int o = 32; o; o >>= 1) {
        bz += __shfl_down(bz, o);
        zq += __shfl_down(zq, o);
        wu += __shfl_down(wu, o);
      }
      if (tid == 0 && own) {
        float mahal = cv[t] - 2.f * bz + zq - wu;
        float ll = -0.5f * (aNv[t] * LOG2PI + slr + ldv[t] + mahal);
        if (!isfinite(ll)) ll = -1e6f;
        out[(size_t)t * 65 + 64] = ll;
      }
      if (own) out[(size_t)t * 65 + tid] = z[tid];
    }
    __syncthreads();
  }
}

extern "C" void kernel_launch(void* const* d_in, const int* in_sizes, int n_in,
                              void* d_out, int out_size, void* d_ws, size_t ws_size,
                              hipStream_t stream) {
  const float* obs = (const float*)d_in[0];
  const float* Lam = (const float*)d_in[1];
  const float* Araw = (const float*)d_in[2];
  const float* logQ = (const float*)d_in[3];
  const float* logR = (const float*)d_in[4];
  float* out = (float*)d_out;

  char* w = (char*)d_ws;
  float* hdr = (float*)w;
  float* Qd = hdr + 64;
  float* Asc = hdr + 128;
  u16* Ab16 = (u16*)(hdr + 4224);
  const size_t MB = (size_t)TT * 4096;
  u16* Sg = (u16*)(w + 32768);
  u16* Gg = Sg + MB;
  u16* Wg = Gg + MB;
  u16* Pb0 = Wg + MB;
  float* bv = (float*)(Pb0 + MB);
  float* cv = bv + (size_t)TT * 64;
  float* aNv = cv + TT;
  float* ldv = aNv + TT;

  k0<<<dim3(1), dim3(256), 0, stream>>>(Araw, logQ, logR, hdr, Qd, Asc, Ab16);
  k1<<<dim3(TT), dim3(512), 0, stream>>>(obs, Lam, logR, Sg, Gg, bv, cv, aNv);
  k2a<<<dim3(TT / 2), dim3(512), 0, stream>>>(Sg, Pb0, hdr, Qd, Ab16);
  k2b<<<dim3(TT), dim3(512), 0, stream>>>(Sg, Pb0, Wg, ldv, hdr, Qd, Ab16);
  k3<<<dim3(TT / OWN), dim3(256), 0, stream>>>(Gg, Wg, bv, cv, aNv, ldv, hdr, Asc, out);
}

// Round 15
// 372.768 us; speedup vs baseline: 1.0648x; 1.0648x over previous
//
#include <hip/hip_runtime.h>

// LTV Kalman filter, GPU-restructured (Woodbury + parallel Riccati).
// R7: H==G -> Hg dropped. k2b: exact reg-GJ + logdet.
// R8 (478.8 -> 448.6): k2b Phase C VALU-lean 256-thread GJ.
// R11 (448.6 -> 375.9): k0 diag fast path.
// R13/R14/R19 (ALL REGRESSED: 407.8/389.1/396.9): three k2a restructurings
// (global scratch, Ub-free ping-pong, product-form Newton) all lost via
// different mechanisms (HBM traffic / barrier count / cache churn).
// k2a is a robust local optimum in its R11 form -> REVERTED EXACTLY, closed.
// R21: k3 barrier merge. k3 = 512 blocks x 16 t-iters x 6 barriers (serial
// chain, ~2 blocks/CU co-resident). Merge the three wave-0-only segments:
// ll-compute folds into uu/z segment; zp(t+1) computed at end of same
// segment (z written+read by the SAME wave -> LDS ordered, no barrier).
// 6 -> 4 barriers/t, numerics bit-identical. Predict k3 ~70 -> ~50-58us,
// total ~355-368. Fallback: >=375 => revert k3.
// R22: identical resubmit of R21 — round 14 hit GPUAcquisitionTimeout.

#define TT 2048
#define NN 256
#define KKD 64
#define PIT 68      // fp32 LDS pitch
#define PB 72       // bf16 LDS pitch
#define PL 264      // bf16 LDS pitch for k1 64x256 L^T tiles
#define LOG2PI 1.8378770664093453f

typedef unsigned short u16;
typedef unsigned int u32;
typedef __attribute__((ext_vector_type(8))) short short8;
typedef __attribute__((ext_vector_type(4))) float f32x4;

__device__ __forceinline__ float bf2f(u16 u) {
  u32 x = ((u32)u) << 16;
  return __uint_as_float(x);
}
__device__ __forceinline__ u16 f2bf(float f) {
  u32 u = __float_as_uint(f);
  u32 r = (u + 0x7fffu + ((u >> 16) & 1u)) >> 16;
  return (u16)r;
}
__device__ __forceinline__ u32 pack2(float a, float b) {
  return (u32)f2bf(a) | ((u32)f2bf(b) << 16);
}
__device__ __forceinline__ float4 ldF4(const float* p) { return *(const float4*)p; }
__device__ __forceinline__ float fin(float v) { return isfinite(v) ? v : 0.f; }
__device__ __forceinline__ float frcp(float x) {
  float r;
  asm("v_rcp_f32 %0, %1" : "=v"(r) : "v"(x));
  return r;
}

// ---------------- K0: scalars ----------------
// R11: isDiag computed FIRST; diag => sig = |a0| exactly (skips B = A^T*A and
// the 64-iter power iteration). Non-diag path unchanged.
__global__ __launch_bounds__(256) void k0(const float* __restrict__ Araw,
                                          const float* __restrict__ logQ,
                                          const float* __restrict__ logR,
                                          float* hdr, float* Qd, float* Asc, u16* Ab16) {
  __shared__ __align__(16) float Bm[64 * PIT];
  __shared__ __align__(16) float red[256];
  __shared__ __align__(16) float vv[64];
  int tid = threadIdx.x;
  if (tid < 64) Qd[tid] = expf(logQ[tid]);
  float r = expf(logR[tid]);
  red[tid] = logf(r + 1e-4f);
  __syncthreads();
  for (int o = 128; o; o >>= 1) {
    if (tid < o) red[tid] += red[tid + o];
    __syncthreads();
  }
  if (tid == 0) hdr[2] = red[0];
  __syncthreads();
  float a0 = Araw[0];
  float okf = 1.0f;
  for (int u = 0; u < 16; ++u) {
    int idx = tid * 16 + u;
    int i = idx >> 6, j = idx & 63;
    float v = Araw[idx];
    bool good = (i == j) ? (v == a0) : (v == 0.0f);
    if (!good) okf = 0.0f;
  }
  red[tid] = okf;
  __syncthreads();
  for (int o = 128; o; o >>= 1) {
    if (tid < o) red[tid] = fminf(red[tid], red[tid + o]);
    __syncthreads();
  }
  float isDiag = red[0];
  __syncthreads();
  float sig;
  if (isDiag != 0.f) {
    sig = fabsf(a0);
  } else {
    for (int u = 0; u < 16; ++u) {
      int idx = tid * 16 + u;
      int i = idx >> 6, j = idx & 63;
      float s = 0.f;
      for (int k = 0; k < 64; ++k) s += Araw[k * 64 + i] * Araw[k * 64 + j];
      Bm[i * PIT + j] = s;
    }
    __syncthreads();
    if (tid < 64) {
      vv[tid] = 1.0f;
      float lam = 0.f;
      for (int it = 0; it < 64; ++it) {
        float ui = 0.f;
        for (int k = 0; k < 64; ++k) ui += Bm[tid * PIT + k] * vv[k];
        float s = ui * ui;
        for (int o = 32; o; o >>= 1) s += __shfl_down(s, o);
        float n2 = __shfl(s, 0);
        float nr = sqrtf(fmaxf(n2, 1e-30f));
        vv[tid] = ui / nr;
        lam = nr;
      }
      if (tid == 0) red[0] = lam;
    }
    __syncthreads();
    sig = sqrtf(fmaxf(red[0], 0.f));
  }
  float scale = 0.98f / (sig + 1e-6f);
  if (tid == 0) {
    hdr[0] = scale * a0;
    hdr[1] = isDiag;
    hdr[3] = sig;
  }
  for (int u = 0; u < 16; ++u) {
    int idx = tid * 16 + u;
    float v = scale * Araw[idx];
    Asc[idx] = v;
    Ab16[idx] = f2bf(v);
  }
}

// ---------------- K1: per-t Woodbury precompute via MFMA (S and G only) ----
__global__ __launch_bounds__(512) void k1(const float* __restrict__ obs,
                                          const float* __restrict__ Lam,
                                          const float* __restrict__ logR,
                                          u16* __restrict__ Sg, u16* __restrict__ Gg,
                                          float* __restrict__ bv,
                                          float* __restrict__ cv, float* __restrict__ aNv) {
  int t = blockIdx.x, tid = threadIdx.x;
  __shared__ __align__(16) u16 Lt[64 * PL];
  __shared__ __align__(16) u16 LtW[64 * PL];
  __shared__ __align__(16) float w1a[NN], w2a[NN], wya[NN];
  __shared__ __align__(16) float red[512];
  int lane = tid & 63, wv = tid >> 6;
  int ln = lane & 15, q = lane >> 4;

  float cpart = 0.f, apart = 0.f;
  if (tid < NN) {
    float y = obs[(size_t)t * NN + tid];
    float r = expf(logR[tid]);
    float re = r + 1e-4f;
    float w1 = 1.0f / re;
    bool m = (y != y);
    w1a[tid] = w1;
    w2a[tid] = m ? 0.f : w1;
    wya[tid] = m ? 0.f : (w1 * y);
    cpart = m ? 0.f : (w1 * y * y);
    apart = m ? 0.f : 1.f;
  }
  const float4* Lsrc = (const float4*)(Lam + (size_t)t * NN * KKD);
  for (int u = 0; u < 8; ++u) {
    int fl = u * 512 + tid;
    float4 v = Lsrc[fl];
    int n = fl >> 4, k0 = (fl & 15) * 4;
    Lt[(k0 + 0) * PL + n] = f2bf(v.x);
    Lt[(k0 + 1) * PL + n] = f2bf(v.y);
    Lt[(k0 + 2) * PL + n] = f2bf(v.z);
    Lt[(k0 + 3) * PL + n] = f2bf(v.w);
  }
  __syncthreads();

  const float* Ws[2] = {w1a, w2a};
  u16* Os[2] = {Sg + (size_t)t * 4096, Gg + (size_t)t * 4096};
#pragma unroll
  for (int m = 0; m < 2; ++m) {
    const float* W = Ws[m];
    for (int u = 0; u < 4; ++u) {
      int fl = u * 512 + tid;
      int row = fl >> 5, c8 = (fl & 31) * 8;
      ushort4 lo = *(const ushort4*)&Lt[row * PL + c8];
      ushort4 hi = *(const ushort4*)&Lt[row * PL + c8 + 4];
      float4 wa = ldF4(&W[c8]);
      float4 wb = ldF4(&W[c8 + 4]);
      ushort4 olo, ohi;
      olo.x = f2bf(bf2f(lo.x) * wa.x); olo.y = f2bf(bf2f(lo.y) * wa.y);
      olo.z = f2bf(bf2f(lo.z) * wa.z); olo.w = f2bf(bf2f(lo.w) * wa.w);
      ohi.x = f2bf(bf2f(hi.x) * wb.x); ohi.y = f2bf(bf2f(hi.y) * wb.y);
      ohi.z = f2bf(bf2f(hi.z) * wb.z); ohi.w = f2bf(bf2f(hi.w) * wb.w);
      *(ushort4*)&LtW[row * PL + c8] = olo;
      *(ushort4*)&LtW[row * PL + c8 + 4] = ohi;
    }
    __syncthreads();
    u16* O = Os[m];
#pragma unroll
    for (int tl = 0; tl < 2; ++tl) {
      int td = wv + tl * 8, ti = td >> 2, tj = td & 3;
      f32x4 acc = {0.f, 0.f, 0.f, 0.f};
#pragma unroll
      for (int n0 = 0; n0 < 256; n0 += 32)
        acc = __builtin_amdgcn_mfma_f32_16x16x32_bf16(
            *(const short8*)&Lt[(ti * 16 + ln) * PL + n0 + q * 8],
            *(const short8*)&LtW[(tj * 16 + ln) * PL + n0 + q * 8], acc, 0, 0, 0);
      int col = tj * 16 + ln, rb = ti * 16 + q * 4;
#pragma unroll
      for (int r = 0; r < 4; ++r) O[(rb + r) * 64 + col] = f2bf(acc[r]);
    }
    __syncthreads();
  }

  {
    int k = tid >> 3, seg = tid & 7;
    float s = 0.f;
    for (int n = seg * 32; n < seg * 32 + 32; n += 4) {
      ushort4 l4 = *(const ushort4*)&Lt[k * PL + n];
      float4 wy = ldF4(&wya[n]);
      s += bf2f(l4.x) * wy.x + bf2f(l4.y) * wy.y + bf2f(l4.z) * wy.z + bf2f(l4.w) * wy.w;
    }
    red[tid] = s;
  }
  __syncthreads();
  if (tid < 64) {
    float acc = 0.f;
#pragma unroll
    for (int s = 0; s < 8; ++s) acc += red[tid * 8 + s];
    bv[(size_t)t * 64 + tid] = acc;
  }
  __syncthreads();
  red[tid] = cpart;
  __syncthreads();
  for (int o = 256; o; o >>= 1) {
    if (tid < o) red[tid] += red[tid + o];
    __syncthreads();
  }
  if (tid == 0) cv[t] = red[0];
  __syncthreads();
  red[tid] = apart;
  __syncthreads();
  for (int o = 256; o; o >>= 1) {
    if (tid < o) red[tid] += red[tid + o];
    __syncthreads();
  }
  if (tid == 0) aNv[t] = red[0];
}

// ---------------- MFMA fragment helpers (16x16x32 bf16) ----------------
__device__ __forceinline__ f32x4 mmLL(const u16* A, const u16* B, int ti, int tj,
                                      int ln, int q, f32x4 acc) {
  int ao = (ti * 16 + ln) * PB + q * 8;
  int bo = (tj * 16 + ln) * PB + q * 8;
#pragma unroll
  for (int k0 = 0; k0 < 64; k0 += 32)
    acc = __builtin_amdgcn_mfma_f32_16x16x32_bf16(*(const short8*)(A + ao + k0),
                                                  *(const short8*)(B + bo + k0), acc, 0, 0, 0);
  return acc;
}
__device__ __forceinline__ f32x4 mmLG(const u16* A, const u16* __restrict__ Bg, int ti,
                                      int tj, int ln, int q, f32x4 acc) {
  int ao = (ti * 16 + ln) * PB + q * 8;
  const u16* bp = Bg + (tj * 16 + ln) * 64 + q * 8;
#pragma unroll
  for (int k0 = 0; k0 < 64; k0 += 32)
    acc = __builtin_amdgcn_mfma_f32_16x16x32_bf16(*(const short8*)(A + ao + k0),
                                                  *(const short8*)(bp + k0), acc, 0, 0, 0);
  return acc;
}
__device__ __forceinline__ f32x4 mmGL(const u16* __restrict__ Ag, const u16* B, int ti,
                                      int tj, int ln, int q, f32x4 acc) {
  const u16* ap = Ag + (ti * 16 + ln) * 64 + q * 8;
  int bo = (tj * 16 + ln) * PB + q * 8;
#pragma unroll
  for (int k0 = 0; k0 < 64; k0 += 32)
    acc = __builtin_amdgcn_mfma_f32_16x16x32_bf16(*(const short8*)(ap + k0),
                                                  *(const short8*)(B + bo + k0), acc, 0, 0, 0);
  return acc;
}
__device__ __forceinline__ void stLDS(u16* Buf, int ti, int tj, int ln, int q, f32x4 v) {
  int col = tj * 16 + ln, rb = ti * 16 + q * 4;
#pragma unroll
  for (int r = 0; r < 4; ++r) Buf[(rb + r) * PB + col] = f2bf(v[r]);
}

// ---------------- K2a: warm-up sweep, GS-paired, Newton inverse -------------
// EXACT R11 FORM (measured 76.8us). Per step: P_pred; M = I + P_pred*S;
// alpha via 3 power-iter matvecs; X = M^-1 via 9 Newton iters
// (X <- 2X - X*M*X, all MFMA bf16); P_upd = W = X * P_pred.
__global__ __launch_bounds__(512) void k2a(const u16* __restrict__ Sg,
                                           u16* __restrict__ Pout,
                                           const float* __restrict__ hdr,
                                           const float* __restrict__ Qd,
                                           const u16* __restrict__ Ab16) {
  int t0 = blockIdx.x * 2, tid = threadIdx.x;
  int lane = tid & 63, w = tid >> 6;
  int ln = lane & 15, q = lane >> 4;

  __shared__ __align__(16) u16 Pp16[64 * PB];  // P_prev / P_pred
  __shared__ __align__(16) u16 Mt[64 * PB];    // M^T bf16
  __shared__ __align__(16) u16 Xr[64 * PB];    // X row-major (also A*P temp)
  __shared__ __align__(16) u16 Xt[64 * PB];    // X transposed
  __shared__ __align__(16) u16 Ub[64 * PB];    // -U = -(X*M)
  __shared__ __align__(16) float pw[600];      // part[512] + v[72] + scalars

  float* part = pw;
  float* v = pw + 512;

  float aS = hdr[0];
  bool diag = (hdr[1] != 0.f);
  int row = tid >> 3, cg = tid & 7;

  for (int st = 0; st < 2; ++st) {
    int t = t0 + st;

    // ---- Phase A: P_pred -> Pp16 ----
    if (st == 0) {
      float pinit = (t == 0) ? 1.f : 0.15f;
      if (diag) {
        float a2 = aS * aS;
        float qr = Qd[row];
        uint4 o;
#pragma unroll
        for (int u = 0; u < 8; u += 2) {
          float va = ((cg * 8 + u == row) ? (a2 * pinit + qr) : 0.f);
          float vb = ((cg * 8 + u + 1 == row) ? (a2 * pinit + qr) : 0.f);
          ((u32*)&o)[u >> 1] = pack2(va, vb);
        }
        *(uint4*)&Pp16[row * PB + cg * 8] = o;
        __syncthreads();
      } else {
        uint4 o;
#pragma unroll
        for (int u = 0; u < 8; u += 2) {
          float va = (cg * 8 + u == row) ? pinit : 0.f;
          float vb = (cg * 8 + u + 1 == row) ? pinit : 0.f;
          ((u32*)&o)[u >> 1] = pack2(va, vb);
        }
        *(uint4*)&Pp16[row * PB + cg * 8] = o;
        __syncthreads();
#pragma unroll
        for (int tl = 0; tl < 2; ++tl) {
          int td = w + tl * 8, ti = td >> 2, tj = td & 3;
          f32x4 acc = {0.f, 0.f, 0.f, 0.f};
          acc = mmGL(Ab16, Pp16, ti, tj, ln, q, acc);
          stLDS(Xr, ti, tj, ln, q, acc);
        }
        __syncthreads();
#pragma unroll
        for (int tl = 0; tl < 2; ++tl) {
          int td = w + tl * 8, ti = td >> 2, tj = td & 3;
          f32x4 acc = {0.f, 0.f, 0.f, 0.f};
          acc = mmLG(Xr, Ab16, ti, tj, ln, q, acc);
          int col = tj * 16 + ln, rb = ti * 16 + q * 4;
#pragma unroll
          for (int r = 0; r < 4; ++r) {
            float vv = acc[r] + ((rb + r) == col ? Qd[rb + r] : 0.f);
            Pp16[(rb + r) * PB + col] = f2bf(vv);
          }
        }
        __syncthreads();
      }
    } else {
      // P_prev already in Pp16 (posterior of t-1)
      if (diag) {
        float a2 = aS * aS;
        float qr = Qd[row];
        uint4 raw = *(const uint4*)&Pp16[row * PB + cg * 8];
        float pv[8];
        pv[0] = bf2f((u16)(raw.x & 0xffff)); pv[1] = bf2f((u16)(raw.x >> 16));
        pv[2] = bf2f((u16)(raw.y & 0xffff)); pv[3] = bf2f((u16)(raw.y >> 16));
        pv[4] = bf2f((u16)(raw.z & 0xffff)); pv[5] = bf2f((u16)(raw.z >> 16));
        pv[6] = bf2f((u16)(raw.w & 0xffff)); pv[7] = bf2f((u16)(raw.w >> 16));
        uint4 o;
#pragma unroll
        for (int u = 0; u < 8; u += 2) {
          float va = a2 * pv[u] + ((cg * 8 + u == row) ? qr : 0.f);
          float vb = a2 * pv[u + 1] + ((cg * 8 + u + 1 == row) ? qr : 0.f);
          ((u32*)&o)[u >> 1] = pack2(va, vb);
        }
        *(uint4*)&Pp16[row * PB + cg * 8] = o;
        __syncthreads();
      } else {
#pragma unroll
        for (int tl = 0; tl < 2; ++tl) {
          int td = w + tl * 8, ti = td >> 2, tj = td & 3;
          f32x4 acc = {0.f, 0.f, 0.f, 0.f};
          acc = mmGL(Ab16, Pp16, ti, tj, ln, q, acc);
          stLDS(Xr, ti, tj, ln, q, acc);
        }
        __syncthreads();
#pragma unroll
        for (int tl = 0; tl < 2; ++tl) {
          int td = w + tl * 8, ti = td >> 2, tj = td & 3;
          f32x4 acc = {0.f, 0.f, 0.f, 0.f};
          acc = mmLG(Xr, Ab16, ti, tj, ln, q, acc);
          int col = tj * 16 + ln, rb = ti * 16 + q * 4;
#pragma unroll
          for (int r = 0; r < 4; ++r) {
            float vv = acc[r] + ((rb + r) == col ? Qd[rb + r] : 0.f);
            Pp16[(rb + r) * PB + col] = f2bf(vv);
          }
        }
        __syncthreads();
      }
    }

    // ---- Phase B: M = I + P_pred * S  -> Mt (transposed, bf16) ----
#pragma unroll
    for (int tl = 0; tl < 2; ++tl) {
      int td = w + tl * 8, ti = td >> 2, tj = td & 3;
      f32x4 acc = {0.f, 0.f, 0.f, 0.f};
      acc = mmLG(Pp16, Sg + (size_t)t * 4096, ti, tj, ln, q, acc);
      int col = tj * 16 + ln, rb = ti * 16 + q * 4;
      ushort4 o4;
      o4.x = f2bf(acc[0] + ((rb + 0) == col ? 1.f : 0.f));
      o4.y = f2bf(acc[1] + ((rb + 1) == col ? 1.f : 0.f));
      o4.z = f2bf(acc[2] + ((rb + 2) == col ? 1.f : 0.f));
      o4.w = f2bf(acc[3] + ((rb + 3) == col ? 1.f : 0.f));
      *(ushort4*)&Mt[col * PB + rb] = o4;  // transposed store
    }
    if (tid < 64) v[tid] = 1.f;
    __syncthreads();

    // ---- Power iteration: 3 matvecs, lambda_est = max3/max2 ----
    float mx[3];
    for (int itp = 0; itp < 3; ++itp) {
      int i = tid & 63, seg = tid >> 6;
      float s = 0.f;
#pragma unroll
      for (int u = 0; u < 8; ++u) {
        int k = seg * 8 + u;
        s += bf2f(Mt[k * PB + i]) * v[k];
      }
      part[tid] = s;
      __syncthreads();
      if (tid < 64) {
        float acc = 0.f;
#pragma unroll
        for (int sg = 0; sg < 8; ++sg) acc += part[tid + 64 * sg];
        v[tid] = acc;
        float m = fabsf(acc);
        for (int o = 32; o; o >>= 1) m = fmaxf(m, __shfl_down(m, o));
        if (tid == 0) pw[584 + itp] = m;
      }
      __syncthreads();
      mx[itp] = pw[584 + itp];
    }
    float lam = mx[2] / fmaxf(mx[1], 1e-20f);
    if (!isfinite(lam) || lam < 1.0f || lam > 1e4f) lam = 64.f;
    float alpha = 1.0f / (lam * 1.02f);

    // ---- Newton: X0 = alpha*I; X <- 2X - X*M*X (9 iters) ----
    f32x4 Xreg[2];
#pragma unroll
    for (int tl = 0; tl < 2; ++tl) {
      int td = w + tl * 8, ti = td >> 2, tj = td & 3;
      int col = tj * 16 + ln, rb = ti * 16 + q * 4;
      ushort4 o4;
#pragma unroll
      for (int r = 0; r < 4; ++r) {
        float xv = ((rb + r) == col) ? alpha : 0.f;
        Xreg[tl][r] = xv;
        Xr[(rb + r) * PB + col] = f2bf(xv);
      }
      o4.x = f2bf(Xreg[tl][0]); o4.y = f2bf(Xreg[tl][1]);
      o4.z = f2bf(Xreg[tl][2]); o4.w = f2bf(Xreg[tl][3]);
      *(ushort4*)&Xt[col * PB + rb] = o4;
    }
    __syncthreads();

    for (int it = 0; it < 9; ++it) {
      // U = X*M  (C = Xr · Mt^T);  store -U row-major
#pragma unroll
      for (int tl = 0; tl < 2; ++tl) {
        int td = w + tl * 8, ti = td >> 2, tj = td & 3;
        f32x4 u = {0.f, 0.f, 0.f, 0.f};
        u = mmLL(Xr, Mt, ti, tj, ln, q, u);
        int col = tj * 16 + ln, rb = ti * 16 + q * 4;
#pragma unroll
        for (int r = 0; r < 4; ++r) Ub[(rb + r) * PB + col] = f2bf(-u[r]);
      }
      __syncthreads();
      // X_new = 2X + (-U)*X
#pragma unroll
      for (int tl = 0; tl < 2; ++tl) {
        int td = w + tl * 8, ti = td >> 2, tj = td & 3;
        f32x4 acc;
#pragma unroll
        for (int r = 0; r < 4; ++r) acc[r] = 2.f * Xreg[tl][r];
        acc = mmLL(Ub, Xt, ti, tj, ln, q, acc);
        Xreg[tl] = acc;
        int col = tj * 16 + ln, rb = ti * 16 + q * 4;
        ushort4 o4;
#pragma unroll
        for (int r = 0; r < 4; ++r) {
          u16 h = f2bf(acc[r]);
          Xr[(rb + r) * PB + col] = h;
          ((u16*)&o4)[r] = h;
        }
        *(ushort4*)&Xt[col * PB + rb] = o4;
      }
      __syncthreads();
    }

    // ---- W = X * P_pred  (= P_upd, short form) ----
    f32x4 pacc[2];
#pragma unroll
    for (int tl = 0; tl < 2; ++tl) {
      int td = w + tl * 8, ti = td >> 2, tj = td & 3;
      f32x4 acc = {0.f, 0.f, 0.f, 0.f};
      acc = mmLL(Xr, Pp16, ti, tj, ln, q, acc);
      pacc[tl] = acc;
      int col = tj * 16 + ln, rb = ti * 16 + q * 4;
#pragma unroll
      for (int r = 0; r < 4; ++r)
        Pout[(size_t)t * 4096 + (rb + r) * 64 + col] = f2bf(fin(acc[r]));
    }
    if (st == 0) {
      __syncthreads();
#pragma unroll
      for (int tl = 0; tl < 2; ++tl) {
        int td = w + tl * 8, ti = td >> 2, tj = td & 3;
        int col = tj * 16 + ln, rb = ti * 16 + q * 4;
#pragma unroll
        for (int r = 0; r < 4; ++r)
          Pp16[(rb + r) * PB + col] = f2bf(fin(pacc[tl][r]));
      }
      __syncthreads();
    }
  }
}

// ---------------- K2b: final sweep — exact GJ, W + logdet only -------------
__global__ __launch_bounds__(512) void k2b(const u16* __restrict__ Sg,
                                           const u16* __restrict__ Pin,
                                           u16* __restrict__ Wout,
                                           float* __restrict__ ldv,
                                           const float* __restrict__ hdr,
                                           const float* __restrict__ Qd,
                                           const u16* __restrict__ Ab16) {
  int t = blockIdx.x, tid = threadIdx.x;
  int lane = tid & 63, w = tid >> 6;
  int ln = lane & 15, q = lane >> 4;

  __shared__ __align__(16) u16 Pp16[64 * PB];
  __shared__ __align__(16) float M32[64 * PIT];
  __shared__ __align__(16) u16 XYb[64 * PB];
  __shared__ __align__(16) float colbuf[2][64];
  __shared__ __align__(16) float pivb[64];

  float aS = hdr[0];
  bool diag = (hdr[1] != 0.f);
  int row = tid >> 3, cg = tid & 7;

  // ---- Phase A: P_pred -> Pp16 ----
  float pv[8];
  if (t == 0) {
#pragma unroll
    for (int u = 0; u < 8; ++u) pv[u] = (cg * 8 + u == row) ? 1.f : 0.f;
  } else {
    uint4 raw = *(const uint4*)(Pin + (size_t)(t - 1) * 4096 + tid * 8);
    pv[0] = bf2f((u16)(raw.x & 0xffff)); pv[1] = bf2f((u16)(raw.x >> 16));
    pv[2] = bf2f((u16)(raw.y & 0xffff)); pv[3] = bf2f((u16)(raw.y >> 16));
    pv[4] = bf2f((u16)(raw.z & 0xffff)); pv[5] = bf2f((u16)(raw.z >> 16));
    pv[6] = bf2f((u16)(raw.w & 0xffff)); pv[7] = bf2f((u16)(raw.w >> 16));
  }
  if (diag) {
    float a2 = aS * aS;
    float qr = Qd[row];
    uint4 o;
#pragma unroll
    for (int u = 0; u < 8; u += 2) {
      float va = a2 * pv[u] + ((cg * 8 + u == row) ? qr : 0.f);
      float vb = a2 * pv[u + 1] + ((cg * 8 + u + 1 == row) ? qr : 0.f);
      ((u32*)&o)[u >> 1] = pack2(va, vb);
    }
    *(uint4*)&Pp16[row * PB + cg * 8] = o;
  } else {
    uint4 o;
    o.x = pack2(pv[0], pv[1]); o.y = pack2(pv[2], pv[3]);
    o.z = pack2(pv[4], pv[5]); o.w = pack2(pv[6], pv[7]);
    *(uint4*)&Pp16[row * PB + cg * 8] = o;
    __syncthreads();
#pragma unroll
    for (int tl = 0; tl < 2; ++tl) {
      int td = w + tl * 8, ti = td >> 2, tj = td & 3;
      f32x4 acc = {0.f, 0.f, 0.f, 0.f};
      acc = mmGL(Ab16, Pp16, ti, tj, ln, q, acc);
      stLDS(XYb, ti, tj, ln, q, acc);
    }
    __syncthreads();
#pragma unroll
    for (int tl = 0; tl < 2; ++tl) {
      int td = w + tl * 8, ti = td >> 2, tj = td & 3;
      f32x4 acc = {0.f, 0.f, 0.f, 0.f};
      acc = mmLG(XYb, Ab16, ti, tj, ln, q, acc);
      int col = tj * 16 + ln, rb = ti * 16 + q * 4;
#pragma unroll
      for (int r = 0; r < 4; ++r) {
        float vv = acc[r] + ((rb + r) == col ? Qd[rb + r] : 0.f);
        Pp16[(rb + r) * PB + col] = f2bf(vv);
      }
    }
  }
  __syncthreads();

  // ---- Phase B: M = I + P_pred * S ----
#pragma unroll
  for (int tl = 0; tl < 2; ++tl) {
    int td = w + tl * 8, ti = td >> 2, tj = td & 3;
    f32x4 acc = {0.f, 0.f, 0.f, 0.f};
    acc = mmLG(Pp16, Sg + (size_t)t * 4096, ti, tj, ln, q, acc);
    int col = tj * 16 + ln, rb = ti * 16 + q * 4;
#pragma unroll
    for (int r = 0; r < 4; ++r) M32[(rb + r) * PIT + col] = acc[r] + ((rb + r) == col ? 1.f : 0.f);
  }
  __syncthreads();

  // ---- Phase C: 256-thread register GJ + pivot capture ----
  int cig = tid >> 4;
  int cjg = tid & 15;
  int i0c = 4 * cig, j0c = 4 * cjg;
  float rr[4][4];
  if (tid < 256) {
#pragma unroll
    for (int k = 0; k < 4; ++k) {
      float4 a = ldF4(&M32[(i0c + k) * PIT + j0c]);
      rr[k][0] = a.x; rr[k][1] = a.y; rr[k][2] = a.z; rr[k][3] = a.w;
    }
    if (cjg == 0)
      *(float4*)&colbuf[0][i0c] = make_float4(rr[0][0], rr[1][0], rr[2][0], rr[3][0]);
  }
  __syncthreads();

  for (int g = 0; g < 16; ++g) {
#pragma unroll
    for (int u = 0; u < 4; ++u) {
      int j = g * 4 + u;
      if (tid < 256) {
        float4 pq = ldF4(&M32[j * PIT + j0c]);
        float pr4[4] = {pq.x, pq.y, pq.z, pq.w};
        float4 fv = ldF4(&colbuf[u & 1][i0c]);
        float fr[4] = {fv.x, fv.y, fv.z, fv.w};
        float piv = colbuf[u & 1][j];
        float pvv = copysignf(fmaxf(fabsf(piv), 1e-12f), piv);
        float prc = frcp(pvv);
        float fp[4];
#pragma unroll
        for (int k = 0; k < 4; ++k) fp[k] = fr[k] * prc;
#pragma unroll
        for (int k = 0; k < 4; ++k)
#pragma unroll
          for (int c = 0; c < 4; ++c) rr[k][c] = fmaf(-fp[k], pr4[c], rr[k][c]);
        if (cjg == g) {
#pragma unroll
          for (int k = 0; k < 4; ++k) rr[k][u] = -fp[k];
        }
        if (cig == g) {
#pragma unroll
          for (int c = 0; c < 4; ++c) rr[u][c] = pr4[c] * prc;
          if (cjg == g) { rr[u][u] = prc; pivb[j] = pvv; }
        }
        int jn = j + 1;
        if (jn < 64) {
          const int un = (u < 3) ? (u + 1) : 0;
          int gn = (u < 3) ? g : (g + 1);
          if (cig == gn)
            *(float4*)&M32[jn * PIT + j0c] =
                make_float4(rr[un][0], rr[un][1], rr[un][2], rr[un][3]);
          if (cjg == gn)
            *(float4*)&colbuf[(u + 1) & 1][i0c] =
                make_float4(rr[0][un], rr[1][un], rr[2][un], rr[3][un]);
        }
      }
      __syncthreads();
    }
  }

  // ---- Phase D: pack inverse regs -> XYb (bf16); parallel logdet ----
  if (tid < 256) {
#pragma unroll
    for (int k = 0; k < 4; ++k) {
      ushort4 o4;
      o4.x = f2bf(rr[k][0]); o4.y = f2bf(rr[k][1]);
      o4.z = f2bf(rr[k][2]); o4.w = f2bf(rr[k][3]);
      *(ushort4*)&XYb[(i0c + k) * PB + j0c] = o4;
    }
  }
  if (tid < 64) {
    float l = logf(fabsf(pivb[tid]));
    for (int o = 32; o; o >>= 1) l += __shfl_down(l, o);
    if (tid == 0) ldv[t] = fin(l);
  }
  __syncthreads();

  // ---- Phase E: W = X * P_pred -> Wout ----
#pragma unroll
  for (int tl = 0; tl < 2; ++tl) {
    int td = w + tl * 8, ti = td >> 2, tj = td & 3;
    f32x4 acc = {0.f, 0.f, 0.f, 0.f};
    acc = mmLL(XYb, Pp16, ti, tj, ln, q, acc);
    int col = tj * 16 + ln, rb = ti * 16 + q * 4;
#pragma unroll
    for (int r = 0; r < 4; ++r)
      Wout[(size_t)t * 4096 + (rb + r) * 64 + col] = f2bf(fin(acc[r]));
  }
}

// ---------------- K3: state + loglik, chunked parallel with warmup ----------
// R21: 4 barriers/t (was 6). The three wave-0-only segments merge: uu/z, ll,
// and zp(t+1) all in one tid<64 segment (single wave -> LDS writes of z are
// ordered before the same wave's reads for the non-diag zp matvec).
// Numerics identical: same ops, same order.
#define OWN 4
#define WARM 12
__global__ __launch_bounds__(256) void k3(const u16* __restrict__ Gg, const u16* __restrict__ Wg,
                                          const float* __restrict__ bv, const float* __restrict__ cv,
                                          const float* __restrict__ aNv, const float* __restrict__ ldv,
                                          const float* __restrict__ hdr, const float* __restrict__ Asc,
                                          float* __restrict__ out) {
  int b = blockIdx.x, tid = threadIdx.x;
  int t0 = b * OWN;
  int tw = t0 - WARM;
  if (tw < 0) tw = 0;
  __shared__ __align__(16) float z[64], zp[64], q[64], wv[64], part[256];
  float aS = hdr[0];
  bool diag = (hdr[1] != 0.f);
  float slr = hdr[2];
  if (tid < 64) {
    z[tid] = 0.f;
    zp[tid] = 0.f;  // z_pred for first iter: A*0 = 0 (both paths)
  }
  __syncthreads();
  for (int t = tw; t < t0 + OWN; ++t) {
    bool own = (t >= t0);
    // seg B: part = G · zp  (all 256 threads)
    {
      int i = tid & 63, seg = tid >> 6;
      const u16* Gr = Gg + (size_t)t * 4096 + i * 64 + seg * 16;
      float s = 0.f;
      for (int u = 0; u < 16; u += 4) {
        ushort4 g4 = *(const ushort4*)(Gr + u);
        const float* zz = &zp[seg * 16 + u];
        s += bf2f(g4.x) * zz[0] + bf2f(g4.y) * zz[1] + bf2f(g4.z) * zz[2] + bf2f(g4.w) * zz[3];
      }
      part[tid] = s;
    }
    __syncthreads();
    // seg C: q, wv  (wave 0)
    if (tid < 64) {
      float qi = part[tid] + part[tid + 64] + part[tid + 128] + part[tid + 192];
      q[tid] = qi;
      wv[tid] = bv[(size_t)t * 64 + tid] - qi;
    }
    __syncthreads();
    // seg D: part = W · wv  (all 256 threads)
    {
      int i = tid & 63, seg = tid >> 6;
      const u16* Wr = Wg + (size_t)t * 4096 + i * 64 + seg * 16;
      float s = 0.f;
      for (int u = 0; u < 16; u += 4) {
        ushort4 g4 = *(const ushort4*)(Wr + u);
        const float* zz = &wv[seg * 16 + u];
        s += bf2f(g4.x) * zz[0] + bf2f(g4.y) * zz[1] + bf2f(g4.z) * zz[2] + bf2f(g4.w) * zz[3];
      }
      part[tid] = s;
    }
    __syncthreads();
    // seg E': uu, z_new, ll, out-writes, zp(t+1)  (wave 0 only)
    if (tid < 64) {
      float ui = part[tid] + part[tid + 64] + part[tid + 128] + part[tid + 192];
      float zpv = zp[tid];
      float zi = zpv + ui;
      float znew = isfinite(zi) ? zi : 0.f;
      z[tid] = znew;
      // log-likelihood reduction (same ops/order as before)
      float bz = bv[(size_t)t * 64 + tid] * zpv;
      float zq = zpv * q[tid];
      float wu = wv[tid] * ui;
      for (int o = 32; o; o >>= 1) {
        bz += __shfl_down(bz, o);
        zq += __shfl_down(zq, o);
        wu += __shfl_down(wu, o);
      }
      if (tid == 0 && own) {
        float mahal = cv[t] - 2.f * bz + zq - wu;
        float ll = -0.5f * (aNv[t] * LOG2PI + slr + ldv[t] + mahal);
        if (!isfinite(ll)) ll = -1e6f;
        out[(size_t)t * 65 + 64] = ll;
      }
      if (own) out[(size_t)t * 65 + tid] = znew;
      // zp for next iteration (single wave: z[] writes above are ordered
      // before these reads within the same wave)
      if (diag)
        zp[tid] = aS * znew;
      else {
        float s = 0.f;
        for (int k = 0; k < 64; k += 4) {
          float4 a = ldF4(&Asc[tid * 64 + k]);
          s += a.x * z[k] + a.y * z[k + 1] + a.z * z[k + 2] + a.w * z[k + 3];
        }
        zp[tid] = s;
      }
    }
    __syncthreads();
  }
}

extern "C" void kernel_launch(void* const* d_in, const int* in_sizes, int n_in,
                              void* d_out, int out_size, void* d_ws, size_t ws_size,
                              hipStream_t stream) {
  const float* obs = (const float*)d_in[0];
  const float* Lam = (const float*)d_in[1];
  const float* Araw = (const float*)d_in[2];
  const float* logQ = (const float*)d_in[3];
  const float* logR = (const float*)d_in[4];
  float* out = (float*)d_out;

  char* w = (char*)d_ws;
  float* hdr = (float*)w;
  float* Qd = hdr + 64;
  float* Asc = hdr + 128;
  u16* Ab16 = (u16*)(hdr + 4224);
  const size_t MB = (size_t)TT * 4096;
  u16* Sg = (u16*)(w + 32768);
  u16* Gg = Sg + MB;
  u16* Wg = Gg + MB;
  u16* Pb0 = Wg + MB;
  float* bv = (float*)(Pb0 + MB);
  float* cv = bv + (size_t)TT * 64;
  float* aNv = cv + TT;
  float* ldv = aNv + TT;

  k0<<<dim3(1), dim3(256), 0, stream>>>(Araw, logQ, logR, hdr, Qd, Asc, Ab16);
  k1<<<dim3(TT), dim3(512), 0, stream>>>(obs, Lam, logR, Sg, Gg, bv, cv, aNv);
  k2a<<<dim3(TT / 2), dim3(512), 0, stream>>>(Sg, Pb0, hdr, Qd, Ab16);
  k2b<<<dim3(TT), dim3(512), 0, stream>>>(Sg, Pb0, Wg, ldv, hdr, Qd, Ab16);
  k3<<<dim3(TT / OWN), dim3(256), 0, stream>>>(Gg, Wg, bv, cv, aNv, ldv, hdr, Asc, out);
}

// Round 16
// 369.328 us; speedup vs baseline: 1.0747x; 1.0093x over previous
//
#include <hip/hip_runtime.h>

// LTV Kalman filter, GPU-restructured (Woodbury + parallel Riccati).
// R7: H==G -> Hg dropped. k2b: exact reg-GJ + logdet.
// R8 (478.8 -> 448.6): k2b Phase C VALU-lean 256-thread GJ.
// R11 (448.6 -> 375.9): k0 diag fast path.
// R13/R14/R19 (ALL REGRESSED): three k2a restructurings lost via different
// mechanisms. k2a closed in its R11 form (76.8us).
// R21 (375.9 -> 372.8): k3 barrier merge 6 -> 4 barriers/t. Kept.
// R23: k1 tail barrier merge. Old tail: bv-reduce (2 bar) + TWO 9-step LDS
// reduction trees with a 512-thread barrier per step (~23 barriers) for two
// scalars (cv, aNv). New: joint 64-wide shfl reduce of (cpart, apart),
// lane0-of-wave partials -> w1a[0..15] (dead after m-loop), 1 barrier,
// tid0 final sum. 23 -> 2 barriers. aNv exact (integer sum); cv fp32
// reassociation only (inside tolerance). Serial-chain model (validated
// R11/R14): k1 ~70-76 -> ~55-65us; total ~355-365.
// Fallback: total >= 372 => revert k1 tail, conclude.

#define TT 2048
#define NN 256
#define KKD 64
#define PIT 68      // fp32 LDS pitch
#define PB 72       // bf16 LDS pitch
#define PL 264      // bf16 LDS pitch for k1 64x256 L^T tiles
#define LOG2PI 1.8378770664093453f

typedef unsigned short u16;
typedef unsigned int u32;
typedef __attribute__((ext_vector_type(8))) short short8;
typedef __attribute__((ext_vector_type(4))) float f32x4;

__device__ __forceinline__ float bf2f(u16 u) {
  u32 x = ((u32)u) << 16;
  return __uint_as_float(x);
}
__device__ __forceinline__ u16 f2bf(float f) {
  u32 u = __float_as_uint(f);
  u32 r = (u + 0x7fffu + ((u >> 16) & 1u)) >> 16;
  return (u16)r;
}
__device__ __forceinline__ u32 pack2(float a, float b) {
  return (u32)f2bf(a) | ((u32)f2bf(b) << 16);
}
__device__ __forceinline__ float4 ldF4(const float* p) { return *(const float4*)p; }
__device__ __forceinline__ float fin(float v) { return isfinite(v) ? v : 0.f; }
__device__ __forceinline__ float frcp(float x) {
  float r;
  asm("v_rcp_f32 %0, %1" : "=v"(r) : "v"(x));
  return r;
}

// ---------------- K0: scalars ----------------
// R11: isDiag computed FIRST; diag => sig = |a0| exactly (skips B = A^T*A and
// the 64-iter power iteration). Non-diag path unchanged.
__global__ __launch_bounds__(256) void k0(const float* __restrict__ Araw,
                                          const float* __restrict__ logQ,
                                          const float* __restrict__ logR,
                                          float* hdr, float* Qd, float* Asc, u16* Ab16) {
  __shared__ __align__(16) float Bm[64 * PIT];
  __shared__ __align__(16) float red[256];
  __shared__ __align__(16) float vv[64];
  int tid = threadIdx.x;
  if (tid < 64) Qd[tid] = expf(logQ[tid]);
  float r = expf(logR[tid]);
  red[tid] = logf(r + 1e-4f);
  __syncthreads();
  for (int o = 128; o; o >>= 1) {
    if (tid < o) red[tid] += red[tid + o];
    __syncthreads();
  }
  if (tid == 0) hdr[2] = red[0];
  __syncthreads();
  float a0 = Araw[0];
  float okf = 1.0f;
  for (int u = 0; u < 16; ++u) {
    int idx = tid * 16 + u;
    int i = idx >> 6, j = idx & 63;
    float v = Araw[idx];
    bool good = (i == j) ? (v == a0) : (v == 0.0f);
    if (!good) okf = 0.0f;
  }
  red[tid] = okf;
  __syncthreads();
  for (int o = 128; o; o >>= 1) {
    if (tid < o) red[tid] = fminf(red[tid], red[tid + o]);
    __syncthreads();
  }
  float isDiag = red[0];
  __syncthreads();
  float sig;
  if (isDiag != 0.f) {
    sig = fabsf(a0);
  } else {
    for (int u = 0; u < 16; ++u) {
      int idx = tid * 16 + u;
      int i = idx >> 6, j = idx & 63;
      float s = 0.f;
      for (int k = 0; k < 64; ++k) s += Araw[k * 64 + i] * Araw[k * 64 + j];
      Bm[i * PIT + j] = s;
    }
    __syncthreads();
    if (tid < 64) {
      vv[tid] = 1.0f;
      float lam = 0.f;
      for (int it = 0; it < 64; ++it) {
        float ui = 0.f;
        for (int k = 0; k < 64; ++k) ui += Bm[tid * PIT + k] * vv[k];
        float s = ui * ui;
        for (int o = 32; o; o >>= 1) s += __shfl_down(s, o);
        float n2 = __shfl(s, 0);
        float nr = sqrtf(fmaxf(n2, 1e-30f));
        vv[tid] = ui / nr;
        lam = nr;
      }
      if (tid == 0) red[0] = lam;
    }
    __syncthreads();
    sig = sqrtf(fmaxf(red[0], 0.f));
  }
  float scale = 0.98f / (sig + 1e-6f);
  if (tid == 0) {
    hdr[0] = scale * a0;
    hdr[1] = isDiag;
    hdr[3] = sig;
  }
  for (int u = 0; u < 16; ++u) {
    int idx = tid * 16 + u;
    float v = scale * Araw[idx];
    Asc[idx] = v;
    Ab16[idx] = f2bf(v);
  }
}

// ---------------- K1: per-t Woodbury precompute via MFMA (S and G only) ----
// R23: tail reductions via joint wave-shuffle (2 barriers, was ~23).
__global__ __launch_bounds__(512) void k1(const float* __restrict__ obs,
                                          const float* __restrict__ Lam,
                                          const float* __restrict__ logR,
                                          u16* __restrict__ Sg, u16* __restrict__ Gg,
                                          float* __restrict__ bv,
                                          float* __restrict__ cv, float* __restrict__ aNv) {
  int t = blockIdx.x, tid = threadIdx.x;
  __shared__ __align__(16) u16 Lt[64 * PL];
  __shared__ __align__(16) u16 LtW[64 * PL];
  __shared__ __align__(16) float w1a[NN], w2a[NN], wya[NN];
  __shared__ __align__(16) float red[512];
  int lane = tid & 63, wv = tid >> 6;
  int ln = lane & 15, q = lane >> 4;

  float cpart = 0.f, apart = 0.f;
  if (tid < NN) {
    float y = obs[(size_t)t * NN + tid];
    float r = expf(logR[tid]);
    float re = r + 1e-4f;
    float w1 = 1.0f / re;
    bool m = (y != y);
    w1a[tid] = w1;
    w2a[tid] = m ? 0.f : w1;
    wya[tid] = m ? 0.f : (w1 * y);
    cpart = m ? 0.f : (w1 * y * y);
    apart = m ? 0.f : 1.f;
  }
  const float4* Lsrc = (const float4*)(Lam + (size_t)t * NN * KKD);
  for (int u = 0; u < 8; ++u) {
    int fl = u * 512 + tid;
    float4 v = Lsrc[fl];
    int n = fl >> 4, k0 = (fl & 15) * 4;
    Lt[(k0 + 0) * PL + n] = f2bf(v.x);
    Lt[(k0 + 1) * PL + n] = f2bf(v.y);
    Lt[(k0 + 2) * PL + n] = f2bf(v.z);
    Lt[(k0 + 3) * PL + n] = f2bf(v.w);
  }
  __syncthreads();

  const float* Ws[2] = {w1a, w2a};
  u16* Os[2] = {Sg + (size_t)t * 4096, Gg + (size_t)t * 4096};
#pragma unroll
  for (int m = 0; m < 2; ++m) {
    const float* W = Ws[m];
    for (int u = 0; u < 4; ++u) {
      int fl = u * 512 + tid;
      int row = fl >> 5, c8 = (fl & 31) * 8;
      ushort4 lo = *(const ushort4*)&Lt[row * PL + c8];
      ushort4 hi = *(const ushort4*)&Lt[row * PL + c8 + 4];
      float4 wa = ldF4(&W[c8]);
      float4 wb = ldF4(&W[c8 + 4]);
      ushort4 olo, ohi;
      olo.x = f2bf(bf2f(lo.x) * wa.x); olo.y = f2bf(bf2f(lo.y) * wa.y);
      olo.z = f2bf(bf2f(lo.z) * wa.z); olo.w = f2bf(bf2f(lo.w) * wa.w);
      ohi.x = f2bf(bf2f(hi.x) * wb.x); ohi.y = f2bf(bf2f(hi.y) * wb.y);
      ohi.z = f2bf(bf2f(hi.z) * wb.z); ohi.w = f2bf(bf2f(hi.w) * wb.w);
      *(ushort4*)&LtW[row * PL + c8] = olo;
      *(ushort4*)&LtW[row * PL + c8 + 4] = ohi;
    }
    __syncthreads();
    u16* O = Os[m];
#pragma unroll
    for (int tl = 0; tl < 2; ++tl) {
      int td = wv + tl * 8, ti = td >> 2, tj = td & 3;
      f32x4 acc = {0.f, 0.f, 0.f, 0.f};
#pragma unroll
      for (int n0 = 0; n0 < 256; n0 += 32)
        acc = __builtin_amdgcn_mfma_f32_16x16x32_bf16(
            *(const short8*)&Lt[(ti * 16 + ln) * PL + n0 + q * 8],
            *(const short8*)&LtW[(tj * 16 + ln) * PL + n0 + q * 8], acc, 0, 0, 0);
      int col = tj * 16 + ln, rb = ti * 16 + q * 4;
#pragma unroll
      for (int r = 0; r < 4; ++r) O[(rb + r) * 64 + col] = f2bf(acc[r]);
    }
    __syncthreads();
  }

  // ---- Tail (R23): bv partials, then ONE merged segment ----
  {
    int k = tid >> 3, seg = tid & 7;
    float s = 0.f;
    for (int n = seg * 32; n < seg * 32 + 32; n += 4) {
      ushort4 l4 = *(const ushort4*)&Lt[k * PL + n];
      float4 wy = ldF4(&wya[n]);
      s += bf2f(l4.x) * wy.x + bf2f(l4.y) * wy.y + bf2f(l4.z) * wy.z + bf2f(l4.w) * wy.w;
    }
    red[tid] = s;
  }
  __syncthreads();
  // merged: bv final sum (wave 0, reads red[0..511]) + joint shuffle reduce
  // of (cpart, apart) across each wave (register-only) -> partials in
  // w1a[0..15] (w1a dead after m-loop; no overlap with red[]).
  if (tid < 64) {
    float acc = 0.f;
#pragma unroll
    for (int s = 0; s < 8; ++s) acc += red[tid * 8 + s];
    bv[(size_t)t * 64 + tid] = acc;
  }
  {
    float c = cpart, a = apart;
    for (int o = 32; o; o >>= 1) {
      c += __shfl_down(c, o);
      a += __shfl_down(a, o);
    }
    if (lane == 0) {
      w1a[wv] = c;
      w1a[8 + wv] = a;
    }
  }
  __syncthreads();
  if (tid == 0) {
    float cs = 0.f, as = 0.f;
#pragma unroll
    for (int i = 0; i < 8; ++i) {
      cs += w1a[i];
      as += w1a[8 + i];
    }
    cv[t] = cs;
    aNv[t] = as;
  }
}

// ---------------- MFMA fragment helpers (16x16x32 bf16) ----------------
__device__ __forceinline__ f32x4 mmLL(const u16* A, const u16* B, int ti, int tj,
                                      int ln, int q, f32x4 acc) {
  int ao = (ti * 16 + ln) * PB + q * 8;
  int bo = (tj * 16 + ln) * PB + q * 8;
#pragma unroll
  for (int k0 = 0; k0 < 64; k0 += 32)
    acc = __builtin_amdgcn_mfma_f32_16x16x32_bf16(*(const short8*)(A + ao + k0),
                                                  *(const short8*)(B + bo + k0), acc, 0, 0, 0);
  return acc;
}
__device__ __forceinline__ f32x4 mmLG(const u16* A, const u16* __restrict__ Bg, int ti,
                                      int tj, int ln, int q, f32x4 acc) {
  int ao = (ti * 16 + ln) * PB + q * 8;
  const u16* bp = Bg + (tj * 16 + ln) * 64 + q * 8;
#pragma unroll
  for (int k0 = 0; k0 < 64; k0 += 32)
    acc = __builtin_amdgcn_mfma_f32_16x16x32_bf16(*(const short8*)(A + ao + k0),
                                                  *(const short8*)(bp + k0), acc, 0, 0, 0);
  return acc;
}
__device__ __forceinline__ f32x4 mmGL(const u16* __restrict__ Ag, const u16* B, int ti,
                                      int tj, int ln, int q, f32x4 acc) {
  const u16* ap = Ag + (ti * 16 + ln) * 64 + q * 8;
  int bo = (tj * 16 + ln) * PB + q * 8;
#pragma unroll
  for (int k0 = 0; k0 < 64; k0 += 32)
    acc = __builtin_amdgcn_mfma_f32_16x16x32_bf16(*(const short8*)(ap + k0),
                                                  *(const short8*)(B + bo + k0), acc, 0, 0, 0);
  return acc;
}
__device__ __forceinline__ void stLDS(u16* Buf, int ti, int tj, int ln, int q, f32x4 v) {
  int col = tj * 16 + ln, rb = ti * 16 + q * 4;
#pragma unroll
  for (int r = 0; r < 4; ++r) Buf[(rb + r) * PB + col] = f2bf(v[r]);
}

// ---------------- K2a: warm-up sweep, GS-paired, Newton inverse -------------
// EXACT R11 FORM (measured 76.8us). Per step: P_pred; M = I + P_pred*S;
// alpha via 3 power-iter matvecs; X = M^-1 via 9 Newton iters
// (X <- 2X - X*M*X, all MFMA bf16); P_upd = W = X * P_pred.
__global__ __launch_bounds__(512) void k2a(const u16* __restrict__ Sg,
                                           u16* __restrict__ Pout,
                                           const float* __restrict__ hdr,
                                           const float* __restrict__ Qd,
                                           const u16* __restrict__ Ab16) {
  int t0 = blockIdx.x * 2, tid = threadIdx.x;
  int lane = tid & 63, w = tid >> 6;
  int ln = lane & 15, q = lane >> 4;

  __shared__ __align__(16) u16 Pp16[64 * PB];  // P_prev / P_pred
  __shared__ __align__(16) u16 Mt[64 * PB];    // M^T bf16
  __shared__ __align__(16) u16 Xr[64 * PB];    // X row-major (also A*P temp)
  __shared__ __align__(16) u16 Xt[64 * PB];    // X transposed
  __shared__ __align__(16) u16 Ub[64 * PB];    // -U = -(X*M)
  __shared__ __align__(16) float pw[600];      // part[512] + v[72] + scalars

  float* part = pw;
  float* v = pw + 512;

  float aS = hdr[0];
  bool diag = (hdr[1] != 0.f);
  int row = tid >> 3, cg = tid & 7;

  for (int st = 0; st < 2; ++st) {
    int t = t0 + st;

    // ---- Phase A: P_pred -> Pp16 ----
    if (st == 0) {
      float pinit = (t == 0) ? 1.f : 0.15f;
      if (diag) {
        float a2 = aS * aS;
        float qr = Qd[row];
        uint4 o;
#pragma unroll
        for (int u = 0; u < 8; u += 2) {
          float va = ((cg * 8 + u == row) ? (a2 * pinit + qr) : 0.f);
          float vb = ((cg * 8 + u + 1 == row) ? (a2 * pinit + qr) : 0.f);
          ((u32*)&o)[u >> 1] = pack2(va, vb);
        }
        *(uint4*)&Pp16[row * PB + cg * 8] = o;
        __syncthreads();
      } else {
        uint4 o;
#pragma unroll
        for (int u = 0; u < 8; u += 2) {
          float va = (cg * 8 + u == row) ? pinit : 0.f;
          float vb = (cg * 8 + u + 1 == row) ? pinit : 0.f;
          ((u32*)&o)[u >> 1] = pack2(va, vb);
        }
        *(uint4*)&Pp16[row * PB + cg * 8] = o;
        __syncthreads();
#pragma unroll
        for (int tl = 0; tl < 2; ++tl) {
          int td = w + tl * 8, ti = td >> 2, tj = td & 3;
          f32x4 acc = {0.f, 0.f, 0.f, 0.f};
          acc = mmGL(Ab16, Pp16, ti, tj, ln, q, acc);
          stLDS(Xr, ti, tj, ln, q, acc);
        }
        __syncthreads();
#pragma unroll
        for (int tl = 0; tl < 2; ++tl) {
          int td = w + tl * 8, ti = td >> 2, tj = td & 3;
          f32x4 acc = {0.f, 0.f, 0.f, 0.f};
          acc = mmLG(Xr, Ab16, ti, tj, ln, q, acc);
          int col = tj * 16 + ln, rb = ti * 16 + q * 4;
#pragma unroll
          for (int r = 0; r < 4; ++r) {
            float vv = acc[r] + ((rb + r) == col ? Qd[rb + r] : 0.f);
            Pp16[(rb + r) * PB + col] = f2bf(vv);
          }
        }
        __syncthreads();
      }
    } else {
      // P_prev already in Pp16 (posterior of t-1)
      if (diag) {
        float a2 = aS * aS;
        float qr = Qd[row];
        uint4 raw = *(const uint4*)&Pp16[row * PB + cg * 8];
        float pv[8];
        pv[0] = bf2f((u16)(raw.x & 0xffff)); pv[1] = bf2f((u16)(raw.x >> 16));
        pv[2] = bf2f((u16)(raw.y & 0xffff)); pv[3] = bf2f((u16)(raw.y >> 16));
        pv[4] = bf2f((u16)(raw.z & 0xffff)); pv[5] = bf2f((u16)(raw.z >> 16));
        pv[6] = bf2f((u16)(raw.w & 0xffff)); pv[7] = bf2f((u16)(raw.w >> 16));
        uint4 o;
#pragma unroll
        for (int u = 0; u < 8; u += 2) {
          float va = a2 * pv[u] + ((cg * 8 + u == row) ? qr : 0.f);
          float vb = a2 * pv[u + 1] + ((cg * 8 + u + 1 == row) ? qr : 0.f);
          ((u32*)&o)[u >> 1] = pack2(va, vb);
        }
        *(uint4*)&Pp16[row * PB + cg * 8] = o;
        __syncthreads();
      } else {
#pragma unroll
        for (int tl = 0; tl < 2; ++tl) {
          int td = w + tl * 8, ti = td >> 2, tj = td & 3;
          f32x4 acc = {0.f, 0.f, 0.f, 0.f};
          acc = mmGL(Ab16, Pp16, ti, tj, ln, q, acc);
          stLDS(Xr, ti, tj, ln, q, acc);
        }
        __syncthreads();
#pragma unroll
        for (int tl = 0; tl < 2; ++tl) {
          int td = w + tl * 8, ti = td >> 2, tj = td & 3;
          f32x4 acc = {0.f, 0.f, 0.f, 0.f};
          acc = mmLG(Xr, Ab16, ti, tj, ln, q, acc);
          int col = tj * 16 + ln, rb = ti * 16 + q * 4;
#pragma unroll
          for (int r = 0; r < 4; ++r) {
            float vv = acc[r] + ((rb + r) == col ? Qd[rb + r] : 0.f);
            Pp16[(rb + r) * PB + col] = f2bf(vv);
          }
        }
        __syncthreads();
      }
    }

    // ---- Phase B: M = I + P_pred * S  -> Mt (transposed, bf16) ----
#pragma unroll
    for (int tl = 0; tl < 2; ++tl) {
      int td = w + tl * 8, ti = td >> 2, tj = td & 3;
      f32x4 acc = {0.f, 0.f, 0.f, 0.f};
      acc = mmLG(Pp16, Sg + (size_t)t * 4096, ti, tj, ln, q, acc);
      int col = tj * 16 + ln, rb = ti * 16 + q * 4;
      ushort4 o4;
      o4.x = f2bf(acc[0] + ((rb + 0) == col ? 1.f : 0.f));
      o4.y = f2bf(acc[1] + ((rb + 1) == col ? 1.f : 0.f));
      o4.z = f2bf(acc[2] + ((rb + 2) == col ? 1.f : 0.f));
      o4.w = f2bf(acc[3] + ((rb + 3) == col ? 1.f : 0.f));
      *(ushort4*)&Mt[col * PB + rb] = o4;  // transposed store
    }
    if (tid < 64) v[tid] = 1.f;
    __syncthreads();

    // ---- Power iteration: 3 matvecs, lambda_est = max3/max2 ----
    float mx[3];
    for (int itp = 0; itp < 3; ++itp) {
      int i = tid & 63, seg = tid >> 6;
      float s = 0.f;
#pragma unroll
      for (int u = 0; u < 8; ++u) {
        int k = seg * 8 + u;
        s += bf2f(Mt[k * PB + i]) * v[k];
      }
      part[tid] = s;
      __syncthreads();
      if (tid < 64) {
        float acc = 0.f;
#pragma unroll
        for (int sg = 0; sg < 8; ++sg) acc += part[tid + 64 * sg];
        v[tid] = acc;
        float m = fabsf(acc);
        for (int o = 32; o; o >>= 1) m = fmaxf(m, __shfl_down(m, o));
        if (tid == 0) pw[584 + itp] = m;
      }
      __syncthreads();
      mx[itp] = pw[584 + itp];
    }
    float lam = mx[2] / fmaxf(mx[1], 1e-20f);
    if (!isfinite(lam) || lam < 1.0f || lam > 1e4f) lam = 64.f;
    float alpha = 1.0f / (lam * 1.02f);

    // ---- Newton: X0 = alpha*I; X <- 2X - X*M*X (9 iters) ----
    f32x4 Xreg[2];
#pragma unroll
    for (int tl = 0; tl < 2; ++tl) {
      int td = w + tl * 8, ti = td >> 2, tj = td & 3;
      int col = tj * 16 + ln, rb = ti * 16 + q * 4;
      ushort4 o4;
#pragma unroll
      for (int r = 0; r < 4; ++r) {
        float xv = ((rb + r) == col) ? alpha : 0.f;
        Xreg[tl][r] = xv;
        Xr[(rb + r) * PB + col] = f2bf(xv);
      }
      o4.x = f2bf(Xreg[tl][0]); o4.y = f2bf(Xreg[tl][1]);
      o4.z = f2bf(Xreg[tl][2]); o4.w = f2bf(Xreg[tl][3]);
      *(ushort4*)&Xt[col * PB + rb] = o4;
    }
    __syncthreads();

    for (int it = 0; it < 9; ++it) {
      // U = X*M  (C = Xr · Mt^T);  store -U row-major
#pragma unroll
      for (int tl = 0; tl < 2; ++tl) {
        int td = w + tl * 8, ti = td >> 2, tj = td & 3;
        f32x4 u = {0.f, 0.f, 0.f, 0.f};
        u = mmLL(Xr, Mt, ti, tj, ln, q, u);
        int col = tj * 16 + ln, rb = ti * 16 + q * 4;
#pragma unroll
        for (int r = 0; r < 4; ++r) Ub[(rb + r) * PB + col] = f2bf(-u[r]);
      }
      __syncthreads();
      // X_new = 2X + (-U)*X
#pragma unroll
      for (int tl = 0; tl < 2; ++tl) {
        int td = w + tl * 8, ti = td >> 2, tj = td & 3;
        f32x4 acc;
#pragma unroll
        for (int r = 0; r < 4; ++r) acc[r] = 2.f * Xreg[tl][r];
        acc = mmLL(Ub, Xt, ti, tj, ln, q, acc);
        Xreg[tl] = acc;
        int col = tj * 16 + ln, rb = ti * 16 + q * 4;
        ushort4 o4;
#pragma unroll
        for (int r = 0; r < 4; ++r) {
          u16 h = f2bf(acc[r]);
          Xr[(rb + r) * PB + col] = h;
          ((u16*)&o4)[r] = h;
        }
        *(ushort4*)&Xt[col * PB + rb] = o4;
      }
      __syncthreads();
    }

    // ---- W = X * P_pred  (= P_upd, short form) ----
    f32x4 pacc[2];
#pragma unroll
    for (int tl = 0; tl < 2; ++tl) {
      int td = w + tl * 8, ti = td >> 2, tj = td & 3;
      f32x4 acc = {0.f, 0.f, 0.f, 0.f};
      acc = mmLL(Xr, Pp16, ti, tj, ln, q, acc);
      pacc[tl] = acc;
      int col = tj * 16 + ln, rb = ti * 16 + q * 4;
#pragma unroll
      for (int r = 0; r < 4; ++r)
        Pout[(size_t)t * 4096 + (rb + r) * 64 + col] = f2bf(fin(acc[r]));
    }
    if (st == 0) {
      __syncthreads();
#pragma unroll
      for (int tl = 0; tl < 2; ++tl) {
        int td = w + tl * 8, ti = td >> 2, tj = td & 3;
        int col = tj * 16 + ln, rb = ti * 16 + q * 4;
#pragma unroll
        for (int r = 0; r < 4; ++r)
          Pp16[(rb + r) * PB + col] = f2bf(fin(pacc[tl][r]));
      }
      __syncthreads();
    }
  }
}

// ---------------- K2b: final sweep — exact GJ, W + logdet only -------------
__global__ __launch_bounds__(512) void k2b(const u16* __restrict__ Sg,
                                           const u16* __restrict__ Pin,
                                           u16* __restrict__ Wout,
                                           float* __restrict__ ldv,
                                           const float* __restrict__ hdr,
                                           const float* __restrict__ Qd,
                                           const u16* __restrict__ Ab16) {
  int t = blockIdx.x, tid = threadIdx.x;
  int lane = tid & 63, w = tid >> 6;
  int ln = lane & 15, q = lane >> 4;

  __shared__ __align__(16) u16 Pp16[64 * PB];
  __shared__ __align__(16) float M32[64 * PIT];
  __shared__ __align__(16) u16 XYb[64 * PB];
  __shared__ __align__(16) float colbuf[2][64];
  __shared__ __align__(16) float pivb[64];

  float aS = hdr[0];
  bool diag = (hdr[1] != 0.f);
  int row = tid >> 3, cg = tid & 7;

  // ---- Phase A: P_pred -> Pp16 ----
  float pv[8];
  if (t == 0) {
#pragma unroll
    for (int u = 0; u < 8; ++u) pv[u] = (cg * 8 + u == row) ? 1.f : 0.f;
  } else {
    uint4 raw = *(const uint4*)(Pin + (size_t)(t - 1) * 4096 + tid * 8);
    pv[0] = bf2f((u16)(raw.x & 0xffff)); pv[1] = bf2f((u16)(raw.x >> 16));
    pv[2] = bf2f((u16)(raw.y & 0xffff)); pv[3] = bf2f((u16)(raw.y >> 16));
    pv[4] = bf2f((u16)(raw.z & 0xffff)); pv[5] = bf2f((u16)(raw.z >> 16));
    pv[6] = bf2f((u16)(raw.w & 0xffff)); pv[7] = bf2f((u16)(raw.w >> 16));
  }
  if (diag) {
    float a2 = aS * aS;
    float qr = Qd[row];
    uint4 o;
#pragma unroll
    for (int u = 0; u < 8; u += 2) {
      float va = a2 * pv[u] + ((cg * 8 + u == row) ? qr : 0.f);
      float vb = a2 * pv[u + 1] + ((cg * 8 + u + 1 == row) ? qr : 0.f);
      ((u32*)&o)[u >> 1] = pack2(va, vb);
    }
    *(uint4*)&Pp16[row * PB + cg * 8] = o;
  } else {
    uint4 o;
    o.x = pack2(pv[0], pv[1]); o.y = pack2(pv[2], pv[3]);
    o.z = pack2(pv[4], pv[5]); o.w = pack2(pv[6], pv[7]);
    *(uint4*)&Pp16[row * PB + cg * 8] = o;
    __syncthreads();
#pragma unroll
    for (int tl = 0; tl < 2; ++tl) {
      int td = w + tl * 8, ti = td >> 2, tj = td & 3;
      f32x4 acc = {0.f, 0.f, 0.f, 0.f};
      acc = mmGL(Ab16, Pp16, ti, tj, ln, q, acc);
      stLDS(XYb, ti, tj, ln, q, acc);
    }
    __syncthreads();
#pragma unroll
    for (int tl = 0; tl < 2; ++tl) {
      int td = w + tl * 8, ti = td >> 2, tj = td & 3;
      f32x4 acc = {0.f, 0.f, 0.f, 0.f};
      acc = mmLG(XYb, Ab16, ti, tj, ln, q, acc);
      int col = tj * 16 + ln, rb = ti * 16 + q * 4;
#pragma unroll
      for (int r = 0; r < 4; ++r) {
        float vv = acc[r] + ((rb + r) == col ? Qd[rb + r] : 0.f);
        Pp16[(rb + r) * PB + col] = f2bf(vv);
      }
    }
  }
  __syncthreads();

  // ---- Phase B: M = I + P_pred * S ----
#pragma unroll
  for (int tl = 0; tl < 2; ++tl) {
    int td = w + tl * 8, ti = td >> 2, tj = td & 3;
    f32x4 acc = {0.f, 0.f, 0.f, 0.f};
    acc = mmLG(Pp16, Sg + (size_t)t * 4096, ti, tj, ln, q, acc);
    int col = tj * 16 + ln, rb = ti * 16 + q * 4;
#pragma unroll
    for (int r = 0; r < 4; ++r) M32[(rb + r) * PIT + col] = acc[r] + ((rb + r) == col ? 1.f : 0.f);
  }
  __syncthreads();

  // ---- Phase C: 256-thread register GJ + pivot capture ----
  int cig = tid >> 4;
  int cjg = tid & 15;
  int i0c = 4 * cig, j0c = 4 * cjg;
  float rr[4][4];
  if (tid < 256) {
#pragma unroll
    for (int k = 0; k < 4; ++k) {
      float4 a = ldF4(&M32[(i0c + k) * PIT + j0c]);
      rr[k][0] = a.x; rr[k][1] = a.y; rr[k][2] = a.z; rr[k][3] = a.w;
    }
    if (cjg == 0)
      *(float4*)&colbuf[0][i0c] = make_float4(rr[0][0], rr[1][0], rr[2][0], rr[3][0]);
  }
  __syncthreads();

  for (int g = 0; g < 16; ++g) {
#pragma unroll
    for (int u = 0; u < 4; ++u) {
      int j = g * 4 + u;
      if (tid < 256) {
        float4 pq = ldF4(&M32[j * PIT + j0c]);
        float pr4[4] = {pq.x, pq.y, pq.z, pq.w};
        float4 fv = ldF4(&colbuf[u & 1][i0c]);
        float fr[4] = {fv.x, fv.y, fv.z, fv.w};
        float piv = colbuf[u & 1][j];
        float pvv = copysignf(fmaxf(fabsf(piv), 1e-12f), piv);
        float prc = frcp(pvv);
        float fp[4];
#pragma unroll
        for (int k = 0; k < 4; ++k) fp[k] = fr[k] * prc;
#pragma unroll
        for (int k = 0; k < 4; ++k)
#pragma unroll
          for (int c = 0; c < 4; ++c) rr[k][c] = fmaf(-fp[k], pr4[c], rr[k][c]);
        if (cjg == g) {
#pragma unroll
          for (int k = 0; k < 4; ++k) rr[k][u] = -fp[k];
        }
        if (cig == g) {
#pragma unroll
          for (int c = 0; c < 4; ++c) rr[u][c] = pr4[c] * prc;
          if (cjg == g) { rr[u][u] = prc; pivb[j] = pvv; }
        }
        int jn = j + 1;
        if (jn < 64) {
          const int un = (u < 3) ? (u + 1) : 0;
          int gn = (u < 3) ? g : (g + 1);
          if (cig == gn)
            *(float4*)&M32[jn * PIT + j0c] =
                make_float4(rr[un][0], rr[un][1], rr[un][2], rr[un][3]);
          if (cjg == gn)
            *(float4*)&colbuf[(u + 1) & 1][i0c] =
                make_float4(rr[0][un], rr[1][un], rr[2][un], rr[3][un]);
        }
      }
      __syncthreads();
    }
  }

  // ---- Phase D: pack inverse regs -> XYb (bf16); parallel logdet ----
  if (tid < 256) {
#pragma unroll
    for (int k = 0; k < 4; ++k) {
      ushort4 o4;
      o4.x = f2bf(rr[k][0]); o4.y = f2bf(rr[k][1]);
      o4.z = f2bf(rr[k][2]); o4.w = f2bf(rr[k][3]);
      *(ushort4*)&XYb[(i0c + k) * PB + j0c] = o4;
    }
  }
  if (tid < 64) {
    float l = logf(fabsf(pivb[tid]));
    for (int o = 32; o; o >>= 1) l += __shfl_down(l, o);
    if (tid == 0) ldv[t] = fin(l);
  }
  __syncthreads();

  // ---- Phase E: W = X * P_pred -> Wout ----
#pragma unroll
  for (int tl = 0; tl < 2; ++tl) {
    int td = w + tl * 8, ti = td >> 2, tj = td & 3;
    f32x4 acc = {0.f, 0.f, 0.f, 0.f};
    acc = mmLL(XYb, Pp16, ti, tj, ln, q, acc);
    int col = tj * 16 + ln, rb = ti * 16 + q * 4;
#pragma unroll
    for (int r = 0; r < 4; ++r)
      Wout[(size_t)t * 4096 + (rb + r) * 64 + col] = f2bf(fin(acc[r]));
  }
}

// ---------------- K3: state + loglik, chunked parallel with warmup ----------
// R21: 4 barriers/t (was 6). The three wave-0-only segments merge: uu/z, ll,
// and zp(t+1) all in one tid<64 segment (single wave -> LDS writes of z are
// ordered before the same wave's reads for the non-diag zp matvec).
// Numerics identical: same ops, same order.
#define OWN 4
#define WARM 12
__global__ __launch_bounds__(256) void k3(const u16* __restrict__ Gg, const u16* __restrict__ Wg,
                                          const float* __restrict__ bv, const float* __restrict__ cv,
                                          const float* __restrict__ aNv, const float* __restrict__ ldv,
                                          const float* __restrict__ hdr, const float* __restrict__ Asc,
                                          float* __restrict__ out) {
  int b = blockIdx.x, tid = threadIdx.x;
  int t0 = b * OWN;
  int tw = t0 - WARM;
  if (tw < 0) tw = 0;
  __shared__ __align__(16) float z[64], zp[64], q[64], wv[64], part[256];
  float aS = hdr[0];
  bool diag = (hdr[1] != 0.f);
  float slr = hdr[2];
  if (tid < 64) {
    z[tid] = 0.f;
    zp[tid] = 0.f;  // z_pred for first iter: A*0 = 0 (both paths)
  }
  __syncthreads();
  for (int t = tw; t < t0 + OWN; ++t) {
    bool own = (t >= t0);
    // seg B: part = G · zp  (all 256 threads)
    {
      int i = tid & 63, seg = tid >> 6;
      const u16* Gr = Gg + (size_t)t * 4096 + i * 64 + seg * 16;
      float s = 0.f;
      for (int u = 0; u < 16; u += 4) {
        ushort4 g4 = *(const ushort4*)(Gr + u);
        const float* zz = &zp[seg * 16 + u];
        s += bf2f(g4.x) * zz[0] + bf2f(g4.y) * zz[1] + bf2f(g4.z) * zz[2] + bf2f(g4.w) * zz[3];
      }
      part[tid] = s;
    }
    __syncthreads();
    // seg C: q, wv  (wave 0)
    if (tid < 64) {
      float qi = part[tid] + part[tid + 64] + part[tid + 128] + part[tid + 192];
      q[tid] = qi;
      wv[tid] = bv[(size_t)t * 64 + tid] - qi;
    }
    __syncthreads();
    // seg D: part = W · wv  (all 256 threads)
    {
      int i = tid & 63, seg = tid >> 6;
      const u16* Wr = Wg + (size_t)t * 4096 + i * 64 + seg * 16;
      float s = 0.f;
      for (int u = 0; u < 16; u += 4) {
        ushort4 g4 = *(const ushort4*)(Wr + u);
        const float* zz = &wv[seg * 16 + u];
        s += bf2f(g4.x) * zz[0] + bf2f(g4.y) * zz[1] + bf2f(g4.z) * zz[2] + bf2f(g4.w) * zz[3];
      }
      part[tid] = s;
    }
    __syncthreads();
    // seg E': uu, z_new, ll, out-writes, zp(t+1)  (wave 0 only)
    if (tid < 64) {
      float ui = part[tid] + part[tid + 64] + part[tid + 128] + part[tid + 192];
      float zpv = zp[tid];
      float zi = zpv + ui;
      float znew = isfinite(zi) ? zi : 0.f;
      z[tid] = znew;
      // log-likelihood reduction (same ops/order as before)
      float bz = bv[(size_t)t * 64 + tid] * zpv;
      float zq = zpv * q[tid];
      float wu = wv[tid] * ui;
      for (int o = 32; o; o >>= 1) {
        bz += __shfl_down(bz, o);
        zq += __shfl_down(zq, o);
        wu += __shfl_down(wu, o);
      }
      if (tid == 0 && own) {
        float mahal = cv[t] - 2.f * bz + zq - wu;
        float ll = -0.5f * (aNv[t] * LOG2PI + slr + ldv[t] + mahal);
        if (!isfinite(ll)) ll = -1e6f;
        out[(size_t)t * 65 + 64] = ll;
      }
      if (own) out[(size_t)t * 65 + tid] = znew;
      // zp for next iteration (single wave: z[] writes above are ordered
      // before these reads within the same wave)
      if (diag)
        zp[tid] = aS * znew;
      else {
        float s = 0.f;
        for (int k = 0; k < 64; k += 4) {
          float4 a = ldF4(&Asc[tid * 64 + k]);
          s += a.x * z[k] + a.y * z[k + 1] + a.z * z[k + 2] + a.w * z[k + 3];
        }
        zp[tid] = s;
      }
    }
    __syncthreads();
  }
}

extern "C" void kernel_launch(void* const* d_in, const int* in_sizes, int n_in,
                              void* d_out, int out_size, void* d_ws, size_t ws_size,
                              hipStream_t stream) {
  const float* obs = (const float*)d_in[0];
  const float* Lam = (const float*)d_in[1];
  const float* Araw = (const float*)d_in[2];
  const float* logQ = (const float*)d_in[3];
  const float* logR = (const float*)d_in[4];
  float* out = (float*)d_out;

  char* w = (char*)d_ws;
  float* hdr = (float*)w;
  float* Qd = hdr + 64;
  float* Asc = hdr + 128;
  u16* Ab16 = (u16*)(hdr + 4224);
  const size_t MB = (size_t)TT * 4096;
  u16* Sg = (u16*)(w + 32768);
  u16* Gg = Sg + MB;
  u16* Wg = Gg + MB;
  u16* Pb0 = Wg + MB;
  float* bv = (float*)(Pb0 + MB);
  float* cv = bv + (size_t)TT * 64;
  float* aNv = cv + TT;
  float* ldv = aNv + TT;

  k0<<<dim3(1), dim3(256), 0, stream>>>(Araw, logQ, logR, hdr, Qd, Asc, Ab16);
  k1<<<dim3(TT), dim3(512), 0, stream>>>(obs, Lam, logR, Sg, Gg, bv, cv, aNv);
  k2a<<<dim3(TT / 2), dim3(512), 0, stream>>>(Sg, Pb0, hdr, Qd, Ab16);
  k2b<<<dim3(TT), dim3(512), 0, stream>>>(Sg, Pb0, Wg, ldv, hdr, Qd, Ab16);
  k3<<<dim3(TT / OWN), dim3(256), 0, stream>>>(Gg, Wg, bv, cv, aNv, ldv, hdr, Asc, out);
}